// Round 6
// baseline (367.915 us; speedup 1.0000x reference)
//
#include <hip/hip_runtime.h>
#include <cstdint>
#include <cstddef>

using u16 = unsigned short;
using u32 = uint32_t;

typedef __attribute__((ext_vector_type(8))) short short8;
typedef __attribute__((ext_vector_type(4))) float floatx4;

#define DEVFN static __device__ __forceinline__

// 0.125 * log2(e): fold attention scale into q, softmax runs in log2 domain
#define QSCALE 0.18033688011112042f

DEVFN u16 f2bf(float f) {
  u32 u = __float_as_uint(f);
  return (u16)((u + 0x7fffu + ((u >> 16) & 1u)) >> 16);
}

DEVFN float b2f(u16 u) { return __uint_as_float(((u32)u) << 16); }

DEVFN void async_load16(const void* g, const void* lds) {
  __builtin_amdgcn_global_load_lds(
      (const __attribute__((address_space(1))) u32*)(uintptr_t)g,
      (__attribute__((address_space(3))) u32*)(u32)(uintptr_t)lds,
      16, 0, 0);
}

DEVFN void cvt4(const float* __restrict__ src, u16* __restrict__ dst, int i) {
  const float4 v = ((const float4*)src)[i];
  ushort4 o;
  o.x = f2bf(v.x); o.y = f2bf(v.y); o.z = f2bf(v.z); o.w = f2bf(v.w);
  ((ushort4*)dst)[i] = o;
}

// ---------------- fused prep: rope tables + all weight cvts + LN1 ----------------
// grid ranges: [0,256) rope | [256,3328) Wqkv | [3328,4352) Wo |
//              [4352,9600) Wi-permute | [9600,12224) Wmlp | [12224,16320) LN1
__global__ __launch_bounds__(256)
void prep_k(const float* __restrict__ Wqkv, const float* __restrict__ Wo,
            const float* __restrict__ Wi, const float* __restrict__ Wmlp,
            const float* __restrict__ hidden, const float* __restrict__ ln1g,
            const float* __restrict__ ln1b,
            u16* __restrict__ wqkv_bf, u16* __restrict__ wo_bf,
            u16* __restrict__ wi_bf, u16* __restrict__ wmlp_bf,
            float* __restrict__ ct, float* __restrict__ st, u16* __restrict__ xn) {
  const int bid = blockIdx.x;
  const int tid = threadIdx.x;
  __shared__ float red[8];
  if (bid < 256) {
    const int i = bid * 256 + tid;
    const int m = i >> 5, f = i & 31;
    const float inv = exp2f((float)f * -0.41524101186092025f);  // 10000^(-f/32)
    const float ang = (float)m * inv;
    ct[i] = cosf(ang);
    st[i] = sinf(ang);
  } else if (bid < 3328) {
    cvt4(Wqkv, wqkv_bf, (bid - 256) * 256 + tid);
  } else if (bid < 4352) {
    cvt4(Wo, wo_bf, (bid - 3328) * 256 + tid);
  } else if (bid < 9600) {
    // Wi permute: dst row p=g*32+c: c<16 -> Wi row g*16+c, else 2624+g*16+(c-16)
    const int i = (bid - 4352) * 256 + tid;
    const int i4 = i * 4;
    const int p = i4 >> 10, kc = i4 & 1023;
    const int g = p >> 5, c = p & 31;
    const int srow = (c < 16) ? (g * 16 + c) : (2624 + g * 16 + (c - 16));
    const float4 v = *(const float4*)(Wi + (size_t)srow * 1024 + kc);
    ushort4 o;
    o.x = f2bf(v.x); o.y = f2bf(v.y); o.z = f2bf(v.z); o.w = f2bf(v.w);
    ((ushort4*)wi_bf)[i] = o;
  } else if (bid < 12224) {
    cvt4(Wmlp, wmlp_bf, (bid - 9600) * 256 + tid);
  } else {
    const int row = bid - 12224;
    const float4 v = ((const float4*)(hidden + (size_t)row * 1024))[tid];
    float s = v.x + v.y + v.z + v.w;
    float ss = v.x * v.x + v.y * v.y + v.z * v.z + v.w * v.w;
#pragma unroll
    for (int d = 32; d > 0; d >>= 1) {
      s += __shfl_xor(s, d);
      ss += __shfl_xor(ss, d);
    }
    const int wave = tid >> 6;
    if ((tid & 63) == 0) { red[wave] = s; red[4 + wave] = ss; }
    __syncthreads();
    s = red[0] + red[1] + red[2] + red[3];
    ss = red[4] + red[5] + red[6] + red[7];
    const float mu = s * (1.f / 1024.f);
    const float var = ss * (1.f / 1024.f) - mu * mu;
    const float rr = rsqrtf(var + 1e-5f);
    const float4 gv = ((const float4*)ln1g)[tid];
    const float4 bv = ((const float4*)ln1b)[tid];
    u16* orow = xn + (size_t)row * 1024 + tid * 4;
    orow[0] = f2bf((v.x - mu) * rr * gv.x + bv.x);
    orow[1] = f2bf((v.y - mu) * rr * gv.y + bv.y);
    orow[2] = f2bf((v.z - mu) * rr * gv.z + bv.z);
    orow[3] = f2bf((v.w - mu) * rr * gv.w + bv.w);
  }
}

// ---------------- reduce 3 partials + residual + layernorm ----------------
__global__ __launch_bounds__(256)
void red_ln_k(const float* __restrict__ resid, const u16* __restrict__ p0,
              const u16* __restrict__ p1, const u16* __restrict__ p2,
              const float* __restrict__ g, const float* __restrict__ bb,
              float* __restrict__ outx, u16* __restrict__ outn) {
  const int row = blockIdx.x;
  const int tid = threadIdx.x;
  const size_t base = (size_t)row * 1024;
  const float4 h = ((const float4*)(resid + base))[tid];
  const ushort4 a = ((const ushort4*)(p0 + base))[tid];
  const ushort4 c = ((const ushort4*)(p1 + base))[tid];
  const ushort4 d = ((const ushort4*)(p2 + base))[tid];
  float4 v;
  v.x = h.x + b2f(a.x) + b2f(c.x) + b2f(d.x);
  v.y = h.y + b2f(a.y) + b2f(c.y) + b2f(d.y);
  v.z = h.z + b2f(a.z) + b2f(c.z) + b2f(d.z);
  v.w = h.w + b2f(a.w) + b2f(c.w) + b2f(d.w);
  float s = v.x + v.y + v.z + v.w;
  float ss = v.x * v.x + v.y * v.y + v.z * v.z + v.w * v.w;
#pragma unroll
  for (int dd = 32; dd > 0; dd >>= 1) {
    s += __shfl_xor(s, dd);
    ss += __shfl_xor(ss, dd);
  }
  __shared__ float red[8];
  const int wave = tid >> 6;
  if ((tid & 63) == 0) { red[wave] = s; red[4 + wave] = ss; }
  __syncthreads();
  s = red[0] + red[1] + red[2] + red[3];
  ss = red[4] + red[5] + red[6] + red[7];
  const float mu = s * (1.f / 1024.f);
  const float var = ss * (1.f / 1024.f) - mu * mu;
  const float rr = rsqrtf(var + 1e-5f);
  ((float4*)(outx + base))[tid] = v;
  const float4 gv = ((const float4*)g)[tid];
  const float4 bv = ((const float4*)bb)[tid];
  u16* orow = outn + base + tid * 4;
  orow[0] = f2bf((v.x - mu) * rr * gv.x + bv.x);
  orow[1] = f2bf((v.y - mu) * rr * gv.y + bv.y);
  orow[2] = f2bf((v.z - mu) * rr * gv.z + bv.z);
  orow[3] = f2bf((v.w - mu) * rr * gv.w + bv.w);
}

// ---------------- final: out += p0+p1+p2+p3 ----------------
__global__ void red_add_k(float* __restrict__ out, const u16* __restrict__ p0,
                          const u16* __restrict__ p1, const u16* __restrict__ p2,
                          const u16* __restrict__ p3) {
  const int i = blockIdx.x * 256 + threadIdx.x;  // 1048576
  float4 v = ((const float4*)out)[i];
  const ushort4 a = ((const ushort4*)p0)[i];
  const ushort4 c = ((const ushort4*)p1)[i];
  const ushort4 d = ((const ushort4*)p2)[i];
  const ushort4 e = ((const ushort4*)p3)[i];
  v.x += b2f(a.x) + b2f(c.x) + b2f(d.x) + b2f(e.x);
  v.y += b2f(a.y) + b2f(c.y) + b2f(d.y) + b2f(e.y);
  v.z += b2f(a.z) + b2f(c.z) + b2f(d.z) + b2f(e.z);
  v.w += b2f(a.w) + b2f(c.w) + b2f(d.w) + b2f(e.w);
  ((float4*)out)[i] = v;
}

// ---------------- attn split-K combine: att = (p0+p1) / (li0+li1) ----------
// In-place over p1 (att aliases p1): elementwise, each thread owns its 4 elems.
__global__ __launch_bounds__(256)
void red_att_k(u16* __restrict__ att, const u16* __restrict__ p0,
               const float* __restrict__ li0, const float* __restrict__ li1) {
  const int i = blockIdx.x * 256 + threadIdx.x;  // 1048576
  const int i4 = i * 4;
  const int row = i4 >> 10;          // b*2048 + m
  const int col = i4 & 1023;
  const int b = row >> 11, m = row & 2047;
  const int h = col >> 6;
  const int bhm = (b * 16 + h) * 2048 + m;
  const float rl = 1.f / (li0[bhm] + li1[bhm]);
  const ushort4 a = ((const ushort4*)p0)[i];
  const ushort4 c = ((const ushort4*)att)[i];
  ushort4 o;
  o.x = f2bf((b2f(a.x) + b2f(c.x)) * rl);
  o.y = f2bf((b2f(a.y) + b2f(c.y)) * rl);
  o.z = f2bf((b2f(a.z) + b2f(c.z)) * rl);
  o.w = f2bf((b2f(a.w) + b2f(c.w)) * rl);
  ((ushort4*)att)[i] = o;
}

// XCD-rectangle swizzle: linear dispatch p -> (tn, tm). Round-robin XCD
// assignment (p%8) gets a contiguous logical range; GROUP_M=8 banding makes
// the ~32 concurrent blocks per XCD an 8m x 4n rectangle (~3MB, fits 4MB L2).
DEVFN void swizzle_tile(int NT, int& tn, int& tm) {
  const int tpx = gridDim.x >> 3;
  const int p = blockIdx.x;
  const int lid = (p & 7) * tpx + (p >> 3);
  const int band = lid / (8 * NT);
  const int rem = lid - band * 8 * NT;
  tn = (rem >> 3) * 128;
  tm = (band * 8 + (rem & 7)) * 128;
}

// ---------------- GEMM: C = A @ B^T, 128x128 tile, BK=32 ----------------
struct EpiArgs {
  const float* bias;
  u16* q; u16* kk; u16* vt;
  u16* outbf;
  const float* ct; const float* st;
};

// EPI 0: QKV (bias + rope + scatter to q/k/vt; q pre-scaled; vt key-permuted)
// EPI 2: gelu-gate -> outbf (act, width 2624)
template <int EPI>
__global__ __launch_bounds__(256, 3)
void gemm_k(const u16* __restrict__ A, const u16* __restrict__ B, int K, int NT,
            EpiArgs ea) {
  __shared__ __align__(16) u16 sA[128 * 32];
  __shared__ __align__(16) u16 sB[128 * 32];
  int tn, tm;
  swizzle_tile(NT, tn, tm);
  const int tid = threadIdx.x;
  const int wave = tid >> 6, lane = tid & 63;
  const int quad = lane >> 4, l15 = lane & 15;
  const int wm = (wave >> 1) * 64, wn = (wave & 1) * 64;

  floatx4 acc[4][4];
#pragma unroll
  for (int i = 0; i < 4; ++i)
#pragma unroll
    for (int j = 0; j < 4; ++j) acc[i][j] = (floatx4){0.f, 0.f, 0.f, 0.f};

  const int srow = lane >> 2;
  const int skc = (lane & 3) * 8;
  const u16* sAr = sA + (wm + l15) * 32 + quad * 8;
  const u16* sBr = sB + (wn + l15) * 32 + quad * 8;

  for (int k0 = 0; k0 < K; k0 += 32) {
#pragma unroll
    for (int j = 0; j < 2; ++j) {
      const int q = wave * 2 + j;
      const int row = q * 16 + srow;
      async_load16(A + (size_t)(tm + row) * K + (k0 + skc), (const char*)sA + q * 1024);
      async_load16(B + (size_t)(tn + row) * K + (k0 + skc), (const char*)sB + q * 1024);
    }
    __syncthreads();
    short8 af[4], bfr[4];
#pragma unroll
    for (int t = 0; t < 4; ++t) af[t] = *(const short8*)(sAr + t * 512);
#pragma unroll
    for (int t = 0; t < 4; ++t) bfr[t] = *(const short8*)(sBr + t * 512);
#pragma unroll
    for (int ti = 0; ti < 4; ++ti)
#pragma unroll
      for (int tj = 0; tj < 4; ++tj)
        acc[ti][tj] = __builtin_amdgcn_mfma_f32_16x16x32_bf16(af[ti], bfr[tj], acc[ti][tj], 0, 0, 0);
    __syncthreads();
  }

  if constexpr (EPI == 0) {
    const int col0 = tn + wn;            // multiple of 64 -> one head per wave
    const int t = col0 >> 10;            // 0=q 1=k 2=v
    const int h = (col0 & 1023) >> 6;
    if (t == 2) {
      // vt with key-permuted token positions: key m -> pos (m&~31)|((m&15)*2)|((m>>4)&1)
#pragma unroll
      for (int ti = 0; ti < 4; ++ti)
#pragma unroll
        for (int r = 0; r < 4; ++r) {
          const int row = tm + wm + ti * 16 + quad * 4 + r;
          const int b = row >> 11, m = row & 2047;
          const int mp = (m & ~31) | ((m & 15) << 1) | ((m >> 4) & 1);
#pragma unroll
          for (int tj = 0; tj < 4; ++tj) {
            const int dh = tj * 16 + l15;
            const float v = acc[ti][tj][r] + ea.bias[col0 + dh];
            ea.vt[((size_t)((b * 16 + h) * 64 + dh)) * 2048 + mp] = f2bf(v);
          }
        }
    } else {
      u16* dst = (t == 0) ? ea.q : ea.kk;
      const float qs = (t == 0) ? QSCALE : 1.f;
#pragma unroll
      for (int ti = 0; ti < 4; ++ti)
#pragma unroll
        for (int r = 0; r < 4; ++r) {
          const int row = tm + wm + ti * 16 + quad * 4 + r;
          const int b = row >> 11, m = row & 2047;
          u16* drow = dst + ((size_t)(b * 16 + h) * 2048 + m) * 64;
#pragma unroll
          for (int tj = 0; tj < 2; ++tj) {
            const int i = tj * 16 + l15;                 // freq index 0..31
            const float x1 = acc[ti][tj][r] + ea.bias[col0 + i];
            const float x2 = acc[ti][tj + 2][r] + ea.bias[col0 + 32 + i];
            const float cs = ea.ct[m * 32 + i];
            const float sn = ea.st[m * 32 + i];
            drow[i] = f2bf((x1 * cs - x2 * sn) * qs);
            drow[32 + i] = f2bf((x1 * sn + x2 * cs) * qs);
          }
        }
    }
  } else {
#pragma unroll
    for (int ti = 0; ti < 4; ++ti)
#pragma unroll
      for (int r = 0; r < 4; ++r) {
        const int row = tm + wm + ti * 16 + quad * 4 + r;
#pragma unroll
        for (int u = 0; u < 2; ++u) {
          const float hin = acc[ti][2 * u][r];
          const float hg = acc[ti][2 * u + 1][r];
          const int a = (((tn + wn) >> 5) + u) * 16 + l15;
          // gelu(h) ~= h * sigmoid(2t), t = 0.7978845608(h + 0.044715 h^3)
          const float t2 = hin + 0.044715f * hin * hin * hin;
          const float e = __builtin_amdgcn_exp2f(t2 * -2.302114768f);  // -2*0.79788*log2e
          const float gl = hin * __builtin_amdgcn_rcpf(1.f + e);
          ea.outbf[(size_t)row * 2624 + a] = f2bf(gl * hg);
        }
      }
  }
}

// ---------------- split-K GEMM: 128x128 tile, bf16 partials ----------------
// z < zsw: kofs=z*kps1, kps=kps1; else kofs=zsw*kps1+(z-zsw)*kps2, kps=kps2
__global__ __launch_bounds__(256, 3)
void gemm_sk4(const u16* __restrict__ A, const u16* __restrict__ B, int K, int NT,
              int kps1, int zsw, int kps2,
              u16* __restrict__ p0, u16* __restrict__ p1,
              u16* __restrict__ p2, u16* __restrict__ p3) {
  __shared__ __align__(16) u16 sA[128 * 32];
  __shared__ __align__(16) u16 sB[128 * 32];
  int tn, tm;
  swizzle_tile(NT, tn, tm);
  const int z = blockIdx.y;
  int kofs, kps;
  if (z < zsw) { kofs = z * kps1; kps = kps1; }
  else { kofs = zsw * kps1 + (z - zsw) * kps2; kps = kps2; }
  const int tid = threadIdx.x;
  const int wave = tid >> 6, lane = tid & 63;
  const int quad = lane >> 4, l15 = lane & 15;
  const int wm = (wave >> 1) * 64, wn = (wave & 1) * 64;

  floatx4 acc[4][4];
#pragma unroll
  for (int i = 0; i < 4; ++i)
#pragma unroll
    for (int j = 0; j < 4; ++j) acc[i][j] = (floatx4){0.f, 0.f, 0.f, 0.f};

  const int srow = lane >> 2;
  const int skc = (lane & 3) * 8;
  const u16* sAr = sA + (wm + l15) * 32 + quad * 8;
  const u16* sBr = sB + (wn + l15) * 32 + quad * 8;

  for (int k0 = 0; k0 < kps; k0 += 32) {
    const int kk = kofs + k0;
#pragma unroll
    for (int j = 0; j < 2; ++j) {
      const int q = wave * 2 + j;
      const int row = q * 16 + srow;
      async_load16(A + (size_t)(tm + row) * K + (kk + skc), (const char*)sA + q * 1024);
      async_load16(B + (size_t)(tn + row) * K + (kk + skc), (const char*)sB + q * 1024);
    }
    __syncthreads();
    short8 af[4], bfr[4];
#pragma unroll
    for (int t = 0; t < 4; ++t) af[t] = *(const short8*)(sAr + t * 512);
#pragma unroll
    for (int t = 0; t < 4; ++t) bfr[t] = *(const short8*)(sBr + t * 512);
#pragma unroll
    for (int ti = 0; ti < 4; ++ti)
#pragma unroll
      for (int tj = 0; tj < 4; ++tj)
        acc[ti][tj] = __builtin_amdgcn_mfma_f32_16x16x32_bf16(af[ti], bfr[tj], acc[ti][tj], 0, 0, 0);
    __syncthreads();
  }

  u16* part = (z == 0) ? p0 : (z == 1) ? p1 : (z == 2) ? p2 : p3;
#pragma unroll
  for (int ti = 0; ti < 4; ++ti)
#pragma unroll
    for (int r = 0; r < 4; ++r) {
      const int row = tm + wm + ti * 16 + quad * 4 + r;
#pragma unroll
      for (int tj = 0; tj < 4; ++tj)
        part[(size_t)row * 1024 + tn + wn + tj * 16 + l15] = f2bf(acc[ti][tj][r]);
    }
}

// ---------------- flash attention, split-K=2, kb-hoist ----------------
// r5 post-mortem: occupancy rose 23->33% but dur stayed 63us -> the limiter
// is the per-CU LDS pipe, not wave count. r5 traffic: (16K+16V+4P) b128
// reads ~12cyc + 16 b32 P-writes ~6cyc = 528 cyc/tile/wave; x16 waves x16
// tiles = ~56us of LDS-pipe time vs 63 measured => LDS-throughput-bound.
// This round hoists the 8 K fragments into registers ONCE per tile (kb[8],
// 32 VGPRs) and reuses them for both g halves: -8 b128 reads -> 432
// cyc/tile/wave, pipe floor ~46us at 4 blocks/CU. V fragments deliberately
// NOT hoisted (stay 4-reg transients) to keep total regs ~120 <= 128 so the
// HW still fits 4 waves/SIMD. launch_bounds stays (256,3): if the allocator
// exceeds 128 we fall back to 3 blocks/CU with zero spills (r4's lesson:
// never force a cap below the kernel's natural footprint).
DEVFN void attn_stage64(const u16* __restrict__ kg, const u16* __restrict__ vtg,
                        size_t bhk, size_t bhv, int key0, int wave, int lane,
                        const u16* sK, const u16* sV) {
#pragma unroll
  for (int j = 0; j < 4; ++j) {
    const int qi = wave * 4 + j;
    if (qi < 8) {
      // K chunk qi: key row = lane, dh range [qi*8, qi*8+8)
      async_load16(kg + bhk + (size_t)(key0 + lane) * 64 + qi * 8,
                   (const char*)sK + qi * 1024);
    } else {
      // V slot vi: dh row = lane, keys (permuted) c*32+kc*8..+8
      const int vi = qi - 8;
      const int c = vi >> 2, kc = vi & 3;
      async_load16(vtg + bhv + (size_t)lane * 2048 + key0 + c * 32 + kc * 8,
                   (const char*)sV + vi * 1024);
    }
  }
}

__global__ __launch_bounds__(256, 3)
void attn_k(const u16* __restrict__ qg, const u16* __restrict__ kg,
            const u16* __restrict__ vtg, const int* __restrict__ mask,
            u16* __restrict__ p0g, u16* __restrict__ p1g,
            float* __restrict__ li0, float* __restrict__ li1) {
  __shared__ __align__(16) u16 sKV[2][8192];     // [buf][ K 4096 u16 | V 4096 u16 ]
  __shared__ __align__(16) u16 sP[4 * 16 * 40];  // per-wave [16 rows][40], reused g,c
  // block remap: 4 consecutive heads per XCD (round-robin dispatch heuristic)
  const int L = blockIdx.x;                      // 1024
  const int xcd = L & 7, idx = L >> 3;           // idx 0..127
  const int bh = (xcd << 2) | (idx >> 5);
  const int local = idx & 31;                    // 16 q-tiles x 2 ksplit
  const int q0 = (local >> 1) * 128;
  const int z = local & 1;
  const int keyBase = z << 10;                   // 0 or 1024
  const int b = bh >> 4, h = bh & 15;
  const int tid = threadIdx.x;
  const int wave = tid >> 6, lane = tid & 63;
  const int quad = lane >> 4, l15 = lane & 15;
  const size_t bhk = (size_t)bh * 2048 * 64;     // kg base for this head
  const size_t bhv = (size_t)bh * 64 * 2048;     // vtg base

  short8 aq[2][2];
#pragma unroll
  for (int g = 0; g < 2; ++g) {
    const u16* qptr = qg + ((size_t)bh * 2048 + q0 + wave * 32 + g * 16 + l15) * 64 + quad * 8;
    aq[g][0] = *(const short8*)qptr;
    aq[g][1] = *(const short8*)(qptr + 32);
  }

  floatx4 o[2][4];
#pragma unroll
  for (int g = 0; g < 2; ++g)
#pragma unroll
    for (int t = 0; t < 4; ++t) o[g][t] = (floatx4){0.f, 0.f, 0.f, 0.f};
  float li[2][4] = {{0.f, 0.f, 0.f, 0.f}, {0.f, 0.f, 0.f, 0.f}};
  const floatx4 z4 = {0.f, 0.f, 0.f, 0.f};

  attn_stage64(kg, vtg, bhk, bhv, keyBase, wave, lane, sKV[0], sKV[0] + 4096);
  __syncthreads();

  int buf = 0;
  for (int kt = 0; kt < 16; ++kt) {
    const u16* sK = sKV[buf];
    const u16* sV = sKV[buf] + 4096;
    const int key0 = keyBase + kt * 64;
    if (kt < 15) {
      // prefetch next K/V tile into the other buffer
      attn_stage64(kg, vtg, bhk, bhv, key0 + 64, wave, lane,
                   sKV[buf ^ 1], sKV[buf ^ 1] + 4096);
    }
    // mask bias for this tile (consumed after QK^T -> latency covered)
    float mbc[4];
#pragma unroll
    for (int tj = 0; tj < 4; ++tj)
      mbc[tj] = (mask[b * 2048 + key0 + tj * 16 + l15] > 0) ? 0.f : -1e30f;
    const float msum = mbc[0] + mbc[1] + mbc[2] + mbc[3];
    const bool allv = __all(msum == 0.f);

    // hoist the 8 K fragments once per tile; reused across both g halves
    short8 kb[8];
#pragma unroll
    for (int tj = 0; tj < 4; ++tj) {
      kb[2 * tj]     = *(const short8*)(sK + quad * 512 + (tj * 16 + l15) * 8);
      kb[2 * tj + 1] = *(const short8*)(sK + (4 + quad) * 512 + (tj * 16 + l15) * 8);
    }

#pragma unroll
    for (int g = 0; g < 2; ++g) {
      // QK^T: 16 q-rows x 64 keys for this half
      floatx4 sacc[4];
      __builtin_amdgcn_s_setprio(1);
#pragma unroll
      for (int tj = 0; tj < 4; ++tj) {
        sacc[tj] = __builtin_amdgcn_mfma_f32_16x16x32_bf16(aq[g][0], kb[2 * tj], z4, 0, 0, 0);
        sacc[tj] = __builtin_amdgcn_mfma_f32_16x16x32_bf16(aq[g][1], kb[2 * tj + 1], sacc[tj], 0, 0, 0);
      }
      __builtin_amdgcn_s_setprio(0);

      // exp + denominator accumulate; add-free fast path for all-valid tiles
      if (allv) {
#pragma unroll
        for (int r = 0; r < 4; ++r) {
          float sum = li[g][r];
#pragma unroll
          for (int tj = 0; tj < 4; ++tj) {
            const float p = __builtin_amdgcn_exp2f(sacc[tj][r]);
            sacc[tj][r] = p;
            sum += p;
          }
          li[g][r] = sum;
        }
      } else {
#pragma unroll
        for (int r = 0; r < 4; ++r) {
          float sum = li[g][r];
#pragma unroll
          for (int tj = 0; tj < 4; ++tj) {
            const float p = __builtin_amdgcn_exp2f(sacc[tj][r] + mbc[tj]);
            sacc[tj][r] = p;
            sum += p;
          }
          li[g][r] = sum;
        }
      }

      // PV: pack P to bf16 via wave-local LDS group (reused across g,c; the
      // pack->read round trip is wave-local and the DS pipe is in-order per
      // wave, so no barrier needed). V fragments read as transients to keep
      // register count under the 128 4-wave/SIMD cliff.
#pragma unroll
      for (int c = 0; c < 2; ++c) {
        u32* pw32 = (u32*)sP + wave * 320;
#pragma unroll
        for (int r = 0; r < 4; ++r) {
          const u32 lo = __float_as_uint(sacc[c * 2][r]) + 0x8000u;
          const u32 hi = __float_as_uint(sacc[c * 2 + 1][r]) + 0x8000u;
          pw32[(quad * 4 + r) * 20 + l15] = __builtin_amdgcn_perm(hi, lo, 0x07060302);
        }
        asm volatile("s_waitcnt lgkmcnt(0)" ::: "memory");
        const short8 ap = *(const short8*)(sP + wave * 640 + l15 * 40 + quad * 8);
        __builtin_amdgcn_s_setprio(1);
#pragma unroll
        for (int tj2 = 0; tj2 < 4; ++tj2) {
          const short8 bv = *(const short8*)(sV + (c * 4 + quad) * 512 + (tj2 * 16 + l15) * 8);
          o[g][tj2] = __builtin_amdgcn_mfma_f32_16x16x32_bf16(ap, bv, o[g][tj2], 0, 0, 0);
        }
        __builtin_amdgcn_s_setprio(0);
      }
    }
    __syncthreads();
    buf ^= 1;
  }

  // reduce li across the 16 lanes of each quad group; write partials
#pragma unroll
  for (int g = 0; g < 2; ++g)
#pragma unroll
    for (int r = 0; r < 4; ++r) {
      float s = li[g][r];
      s += __shfl_xor(s, 1);
      s += __shfl_xor(s, 2);
      s += __shfl_xor(s, 4);
      s += __shfl_xor(s, 8);
      li[g][r] = s;
    }

  u16* pz = z ? p1g : p0g;
  float* lz = z ? li1 : li0;
  if (l15 == 0) {
#pragma unroll
    for (int g = 0; g < 2; ++g)
#pragma unroll
      for (int r = 0; r < 4; ++r) {
        const int m = q0 + wave * 32 + g * 16 + quad * 4 + r;
        lz[(size_t)bh * 2048 + m] = li[g][r];
      }
  }

#pragma unroll
  for (int g = 0; g < 2; ++g)
#pragma unroll
    for (int tj = 0; tj < 4; ++tj)
#pragma unroll
      for (int r = 0; r < 4; ++r) {
        const int m = q0 + wave * 32 + g * 16 + quad * 4 + r;
        pz[((size_t)b * 2048 + m) * 1024 + h * 64 + tj * 16 + l15] = f2bf(o[g][tj][r]);
      }
}

// ---------------- host ----------------
// ws layout (bytes)
static const size_t OFF_WQKV = 0;                       // 3072*1024 bf16; attn li / mlp partial3
static const size_t OFF_WO   = 6291456;                 // 1024*1024 bf16
static const size_t OFF_WI   = 8388608;                 // 5248*1024 bf16; -> mlp partial2
static const size_t OFF_WMLP = 19136512;                // 1024*2624 bf16
static const size_t OFF_XN   = 24510464;                // xn / attn p0 / xn2 / mlp partial0
static const size_t OFF_Q    = 32899072;                // q -> Wo partial0 -> act[0:]
static const size_t OFF_K    = 41287680;                // k -> Wo partial1 -> act cont.
static const size_t OFF_VT   = 49676288;                // vt -> Wo partial2 -> act tail
static const size_t OFF_ATT  = 58064896;                // rope -> attn p1 -> att -> mlp partial1
static const size_t OFF_ROPE = OFF_ATT;
static const size_t WS_NEED  = 66453504;

extern "C" void kernel_launch(void* const* d_in, const int* in_sizes, int n_in,
                              void* d_out, int out_size, void* d_ws, size_t ws_size,
                              hipStream_t stream) {
  (void)in_sizes; (void)n_in; (void)out_size;
  if (ws_size < WS_NEED) return;

  const float* hidden = (const float*)d_in[0];
  const int*   mask   = (const int*)d_in[1];
  const float* ln1g   = (const float*)d_in[2];
  const float* ln1b   = (const float*)d_in[3];
  const float* Wqkv   = (const float*)d_in[4];
  const float* Wqkvb  = (const float*)d_in[5];
  const float* Wo     = (const float*)d_in[6];
  const float* ln2g   = (const float*)d_in[7];
  const float* ln2b   = (const float*)d_in[8];
  const float* Wi     = (const float*)d_in[9];
  const float* Wmlp   = (const float*)d_in[10];
  float* out = (float*)d_out;
  char* ws = (char*)d_ws;

  u16* wqkv_bf = (u16*)(ws + OFF_WQKV);
  u16* wo_bf   = (u16*)(ws + OFF_WO);
  u16* wi_bf   = (u16*)(ws + OFF_WI);
  u16* wmlp_bf = (u16*)(ws + OFF_WMLP);
  u16* xn      = (u16*)(ws + OFF_XN);
  u16* qb      = (u16*)(ws + OFF_Q);
  u16* kb      = (u16*)(ws + OFF_K);
  u16* vtb     = (u16*)(ws + OFF_VT);
  u16* att     = (u16*)(ws + OFF_ATT);
  u16* act     = (u16*)(ws + OFF_Q);                    // 21.5MB spans q/k/vt regions
  float* ct    = (float*)(ws + OFF_ROPE);
  float* st    = (float*)(ws + OFF_ROPE + 262144);
  u16* ap0     = (u16*)(ws + OFF_XN);                   // attn partial z=0 (xn dead)
  u16* ap1     = (u16*)(ws + OFF_ATT);                  // attn partial z=1 (= att, in-place)
  float* li0   = (float*)(ws + OFF_WQKV);               // wqkv_bf dead post-QKV gemm
  float* li1   = (float*)(ws + OFF_WQKV + 262144);
  u16* wp0     = (u16*)(ws + OFF_Q);                    // Wo partials (q/k/vt dead post-attn)
  u16* wp1     = (u16*)(ws + OFF_K);
  u16* wp2     = (u16*)(ws + OFF_VT);
  u16* mp0     = (u16*)(ws + OFF_XN);                   // xn dead after Wi gemm
  u16* mp1     = (u16*)(ws + OFF_ATT);                  // att dead after Wo gemm
  u16* mp2     = (u16*)(ws + OFF_WI);                   // wi_bf dead after Wi gemm
  u16* mp3     = (u16*)(ws + OFF_WQKV);                 // wqkv+li dead by mlp time

  prep_k<<<16320, 256, 0, stream>>>(Wqkv, Wo, Wi, Wmlp, hidden, ln1g, ln1b,
                                    wqkv_bf, wo_bf, wi_bf, wmlp_bf, ct, st, xn);

  EpiArgs e1 = {Wqkvb, qb, kb, vtb, nullptr, ct, st};
  gemm_k<0><<<768, 256, 0, stream>>>(xn, wqkv_bf, 1024, 24, e1);

  attn_k<<<dim3(1024), 256, 0, stream>>>(qb, kb, vtb, mask, ap0, ap1, li0, li1);
  red_att_k<<<4096, 256, 0, stream>>>(att, ap0, li0, li1);

  gemm_sk4<<<dim3(256, 3), 256, 0, stream>>>(att, wo_bf, 1024, 8, 352, 2, 320,
                                             wp0, wp1, wp2, wp2);
  red_ln_k<<<4096, 256, 0, stream>>>(hidden, wp0, wp1, wp2, ln2g, ln2b, out, xn);

  EpiArgs e3 = {nullptr, nullptr, nullptr, nullptr, act, nullptr, nullptr};
  gemm_k<2><<<1312, 256, 0, stream>>>(xn, wi_bf, 1024, 41, e3);

  gemm_sk4<<<dim3(256, 4), 256, 0, stream>>>(act, wmlp_bf, 2624, 8, 672, 2, 640,
                                             mp0, mp1, mp2, mp3);
  red_add_k<<<4096, 256, 0, stream>>>(out, mp0, mp1, mp2, mp3);
}

// Round 7
// 345.410 us; speedup vs baseline: 1.0652x; 1.0652x over previous
//
#include <hip/hip_runtime.h>
#include <cstdint>
#include <cstddef>

using u16 = unsigned short;
using u32 = uint32_t;

typedef __attribute__((ext_vector_type(8))) short short8;
typedef __attribute__((ext_vector_type(4))) float floatx4;
typedef __attribute__((ext_vector_type(4))) unsigned int uintx4;

#define DEVFN static __device__ __forceinline__

// 0.125 * log2(e): fold attention scale into q, softmax runs in log2 domain
#define QSCALE 0.18033688011112042f

DEVFN u16 f2bf(float f) {
  u32 u = __float_as_uint(f);
  return (u16)((u + 0x7fffu + ((u >> 16) & 1u)) >> 16);
}

DEVFN float b2f(u16 u) { return __uint_as_float(((u32)u) << 16); }

// pack two f32 -> u32 of 2 bf16 (lo in low half); round-add as elsewhere
DEVFN u32 pkbf(float lo, float hi) {
  return __builtin_amdgcn_perm(__float_as_uint(hi) + 0x8000u,
                               __float_as_uint(lo) + 0x8000u, 0x07060302u);
}

DEVFN void async_load16(const void* g, const void* lds) {
  __builtin_amdgcn_global_load_lds(
      (const __attribute__((address_space(1))) u32*)(uintptr_t)g,
      (__attribute__((address_space(3))) u32*)(u32)(uintptr_t)lds,
      16, 0, 0);
}

DEVFN void cvt4(const float* __restrict__ src, u16* __restrict__ dst, int i) {
  const float4 v = ((const float4*)src)[i];
  ushort4 o;
  o.x = f2bf(v.x); o.y = f2bf(v.y); o.z = f2bf(v.z); o.w = f2bf(v.w);
  ((ushort4*)dst)[i] = o;
}

// ---------------- fused prep: rope tables + all weight cvts + LN1 ----------------
// grid ranges: [0,256) rope | [256,3328) Wqkv | [3328,4352) Wo |
//              [4352,9600) Wi-permute | [9600,12224) Wmlp | [12224,16320) LN1
__global__ __launch_bounds__(256)
void prep_k(const float* __restrict__ Wqkv, const float* __restrict__ Wo,
            const float* __restrict__ Wi, const float* __restrict__ Wmlp,
            const float* __restrict__ hidden, const float* __restrict__ ln1g,
            const float* __restrict__ ln1b,
            u16* __restrict__ wqkv_bf, u16* __restrict__ wo_bf,
            u16* __restrict__ wi_bf, u16* __restrict__ wmlp_bf,
            float* __restrict__ ct, float* __restrict__ st, u16* __restrict__ xn) {
  const int bid = blockIdx.x;
  const int tid = threadIdx.x;
  __shared__ float red[8];
  if (bid < 256) {
    const int i = bid * 256 + tid;
    const int m = i >> 5, f = i & 31;
    const float inv = exp2f((float)f * -0.41524101186092025f);  // 10000^(-f/32)
    const float ang = (float)m * inv;
    ct[i] = cosf(ang);
    st[i] = sinf(ang);
  } else if (bid < 3328) {
    cvt4(Wqkv, wqkv_bf, (bid - 256) * 256 + tid);
  } else if (bid < 4352) {
    cvt4(Wo, wo_bf, (bid - 3328) * 256 + tid);
  } else if (bid < 9600) {
    // Wi permute: dst row p=g*32+c: c<16 -> Wi row g*16+c, else 2624+g*16+(c-16)
    const int i = (bid - 4352) * 256 + tid;
    const int i4 = i * 4;
    const int p = i4 >> 10, kc = i4 & 1023;
    const int g = p >> 5, c = p & 31;
    const int srow = (c < 16) ? (g * 16 + c) : (2624 + g * 16 + (c - 16));
    const float4 v = *(const float4*)(Wi + (size_t)srow * 1024 + kc);
    ushort4 o;
    o.x = f2bf(v.x); o.y = f2bf(v.y); o.z = f2bf(v.z); o.w = f2bf(v.w);
    ((ushort4*)wi_bf)[i] = o;
  } else if (bid < 12224) {
    cvt4(Wmlp, wmlp_bf, (bid - 9600) * 256 + tid);
  } else {
    const int row = bid - 12224;
    const float4 v = ((const float4*)(hidden + (size_t)row * 1024))[tid];
    float s = v.x + v.y + v.z + v.w;
    float ss = v.x * v.x + v.y * v.y + v.z * v.z + v.w * v.w;
#pragma unroll
    for (int d = 32; d > 0; d >>= 1) {
      s += __shfl_xor(s, d);
      ss += __shfl_xor(ss, d);
    }
    const int wave = tid >> 6;
    if ((tid & 63) == 0) { red[wave] = s; red[4 + wave] = ss; }
    __syncthreads();
    s = red[0] + red[1] + red[2] + red[3];
    ss = red[4] + red[5] + red[6] + red[7];
    const float mu = s * (1.f / 1024.f);
    const float var = ss * (1.f / 1024.f) - mu * mu;
    const float rr = rsqrtf(var + 1e-5f);
    const float4 gv = ((const float4*)ln1g)[tid];
    const float4 bv = ((const float4*)ln1b)[tid];
    u16* orow = xn + (size_t)row * 1024 + tid * 4;
    orow[0] = f2bf((v.x - mu) * rr * gv.x + bv.x);
    orow[1] = f2bf((v.y - mu) * rr * gv.y + bv.y);
    orow[2] = f2bf((v.z - mu) * rr * gv.z + bv.z);
    orow[3] = f2bf((v.w - mu) * rr * gv.w + bv.w);
  }
}

// ---------------- reduce 3 partials + residual + layernorm ----------------
__global__ __launch_bounds__(256)
void red_ln_k(const float* __restrict__ resid, const u16* __restrict__ p0,
              const u16* __restrict__ p1, const u16* __restrict__ p2,
              const float* __restrict__ g, const float* __restrict__ bb,
              float* __restrict__ outx, u16* __restrict__ outn) {
  const int row = blockIdx.x;
  const int tid = threadIdx.x;
  const size_t base = (size_t)row * 1024;
  const float4 h = ((const float4*)(resid + base))[tid];
  const ushort4 a = ((const ushort4*)(p0 + base))[tid];
  const ushort4 c = ((const ushort4*)(p1 + base))[tid];
  const ushort4 d = ((const ushort4*)(p2 + base))[tid];
  float4 v;
  v.x = h.x + b2f(a.x) + b2f(c.x) + b2f(d.x);
  v.y = h.y + b2f(a.y) + b2f(c.y) + b2f(d.y);
  v.z = h.z + b2f(a.z) + b2f(c.z) + b2f(d.z);
  v.w = h.w + b2f(a.w) + b2f(c.w) + b2f(d.w);
  float s = v.x + v.y + v.z + v.w;
  float ss = v.x * v.x + v.y * v.y + v.z * v.z + v.w * v.w;
#pragma unroll
  for (int dd = 32; dd > 0; dd >>= 1) {
    s += __shfl_xor(s, dd);
    ss += __shfl_xor(ss, dd);
  }
  __shared__ float red[8];
  const int wave = tid >> 6;
  if ((tid & 63) == 0) { red[wave] = s; red[4 + wave] = ss; }
  __syncthreads();
  s = red[0] + red[1] + red[2] + red[3];
  ss = red[4] + red[5] + red[6] + red[7];
  const float mu = s * (1.f / 1024.f);
  const float var = ss * (1.f / 1024.f) - mu * mu;
  const float rr = rsqrtf(var + 1e-5f);
  ((float4*)(outx + base))[tid] = v;
  const float4 gv = ((const float4*)g)[tid];
  const float4 bv = ((const float4*)bb)[tid];
  u16* orow = outn + base + tid * 4;
  orow[0] = f2bf((v.x - mu) * rr * gv.x + bv.x);
  orow[1] = f2bf((v.y - mu) * rr * gv.y + bv.y);
  orow[2] = f2bf((v.z - mu) * rr * gv.z + bv.z);
  orow[3] = f2bf((v.w - mu) * rr * gv.w + bv.w);
}

// ---------------- final: out += p0+p1+p2+p3 ----------------
__global__ void red_add_k(float* __restrict__ out, const u16* __restrict__ p0,
                          const u16* __restrict__ p1, const u16* __restrict__ p2,
                          const u16* __restrict__ p3) {
  const int i = blockIdx.x * 256 + threadIdx.x;  // 1048576
  float4 v = ((const float4*)out)[i];
  const ushort4 a = ((const ushort4*)p0)[i];
  const ushort4 c = ((const ushort4*)p1)[i];
  const ushort4 d = ((const ushort4*)p2)[i];
  const ushort4 e = ((const ushort4*)p3)[i];
  v.x += b2f(a.x) + b2f(c.x) + b2f(d.x) + b2f(e.x);
  v.y += b2f(a.y) + b2f(c.y) + b2f(d.y) + b2f(e.y);
  v.z += b2f(a.z) + b2f(c.z) + b2f(d.z) + b2f(e.z);
  v.w += b2f(a.w) + b2f(c.w) + b2f(d.w) + b2f(e.w);
  ((float4*)out)[i] = v;
}

// ---------------- attn split-K combine: att = (p0+p1) / (li0+li1) ----------
// In-place over p1 (att aliases p1): elementwise, each thread owns its 4 elems.
__global__ __launch_bounds__(256)
void red_att_k(u16* __restrict__ att, const u16* __restrict__ p0,
               const float* __restrict__ li0, const float* __restrict__ li1) {
  const int i = blockIdx.x * 256 + threadIdx.x;  // 1048576
  const int i4 = i * 4;
  const int row = i4 >> 10;          // b*2048 + m
  const int col = i4 & 1023;
  const int b = row >> 11, m = row & 2047;
  const int h = col >> 6;
  const int bhm = (b * 16 + h) * 2048 + m;
  const float rl = 1.f / (li0[bhm] + li1[bhm]);
  const ushort4 a = ((const ushort4*)p0)[i];
  const ushort4 c = ((const ushort4*)att)[i];
  ushort4 o;
  o.x = f2bf((b2f(a.x) + b2f(c.x)) * rl);
  o.y = f2bf((b2f(a.y) + b2f(c.y)) * rl);
  o.z = f2bf((b2f(a.z) + b2f(c.z)) * rl);
  o.w = f2bf((b2f(a.w) + b2f(c.w)) * rl);
  ((ushort4*)att)[i] = o;
}

// XCD-rectangle swizzle: linear dispatch p -> (tn, tm). Round-robin XCD
// assignment (p%8) gets a contiguous logical range; GROUP_M=8 banding makes
// the ~32 concurrent blocks per XCD an 8m x 4n rectangle (~3MB, fits 4MB L2).
DEVFN void swizzle_tile(int NT, int& tn, int& tm) {
  const int tpx = gridDim.x >> 3;
  const int p = blockIdx.x;
  const int lid = (p & 7) * tpx + (p >> 3);
  const int band = lid / (8 * NT);
  const int rem = lid - band * 8 * NT;
  tn = (rem >> 3) * 128;
  tm = (band * 8 + (rem & 7)) * 128;
}

// ---------------- GEMM: C = A @ B^T, 128x128 tile, BK=32 ----------------
struct EpiArgs {
  const float* bias;
  u16* q; u16* kk; u16* vt;
  u16* outbf;
  const float* ct; const float* st;
};

// EPI 0: QKV (bias + rope + scatter to q/k/vt; q pre-scaled; vt key-permuted)
// EPI 2: gelu-gate -> outbf (act, width 2624)
template <int EPI>
__global__ __launch_bounds__(256, 3)
void gemm_k(const u16* __restrict__ A, const u16* __restrict__ B, int K, int NT,
            EpiArgs ea) {
  __shared__ __align__(16) u16 sA[128 * 32];
  __shared__ __align__(16) u16 sB[128 * 32];
  int tn, tm;
  swizzle_tile(NT, tn, tm);
  const int tid = threadIdx.x;
  const int wave = tid >> 6, lane = tid & 63;
  const int quad = lane >> 4, l15 = lane & 15;
  const int wm = (wave >> 1) * 64, wn = (wave & 1) * 64;

  floatx4 acc[4][4];
#pragma unroll
  for (int i = 0; i < 4; ++i)
#pragma unroll
    for (int j = 0; j < 4; ++j) acc[i][j] = (floatx4){0.f, 0.f, 0.f, 0.f};

  const int srow = lane >> 2;
  const int skc = (lane & 3) * 8;
  const u16* sAr = sA + (wm + l15) * 32 + quad * 8;
  const u16* sBr = sB + (wn + l15) * 32 + quad * 8;

  for (int k0 = 0; k0 < K; k0 += 32) {
#pragma unroll
    for (int j = 0; j < 2; ++j) {
      const int q = wave * 2 + j;
      const int row = q * 16 + srow;
      async_load16(A + (size_t)(tm + row) * K + (k0 + skc), (const char*)sA + q * 1024);
      async_load16(B + (size_t)(tn + row) * K + (k0 + skc), (const char*)sB + q * 1024);
    }
    __syncthreads();
    short8 af[4], bfr[4];
#pragma unroll
    for (int t = 0; t < 4; ++t) af[t] = *(const short8*)(sAr + t * 512);
#pragma unroll
    for (int t = 0; t < 4; ++t) bfr[t] = *(const short8*)(sBr + t * 512);
#pragma unroll
    for (int ti = 0; ti < 4; ++ti)
#pragma unroll
      for (int tj = 0; tj < 4; ++tj)
        acc[ti][tj] = __builtin_amdgcn_mfma_f32_16x16x32_bf16(af[ti], bfr[tj], acc[ti][tj], 0, 0, 0);
    __syncthreads();
  }

  if constexpr (EPI == 0) {
    const int col0 = tn + wn;            // multiple of 64 -> one head per wave
    const int t = col0 >> 10;            // 0=q 1=k 2=v
    const int h = (col0 & 1023) >> 6;
    if (t == 2) {
      // vt with key-permuted token positions matching the swapped-QKT P-pack:
      // within each 32-key block, key bits m4 m3 m2 m1 m0 -> m3 m2 m4 m1 m0
      // (virtual key v = tj-block*? -- see attn_k P-pack derivation)
#pragma unroll
      for (int ti = 0; ti < 4; ++ti)
#pragma unroll
        for (int r = 0; r < 4; ++r) {
          const int row = tm + wm + ti * 16 + quad * 4 + r;
          const int b = row >> 11, m = row & 2047;
          const int mp = (m & ~31) | ((m & 12) << 1) | ((m & 16) >> 2) | (m & 3);
#pragma unroll
          for (int tj = 0; tj < 4; ++tj) {
            const int dh = tj * 16 + l15;
            const float v = acc[ti][tj][r] + ea.bias[col0 + dh];
            ea.vt[((size_t)((b * 16 + h) * 64 + dh)) * 2048 + mp] = f2bf(v);
          }
        }
    } else {
      u16* dst = (t == 0) ? ea.q : ea.kk;
      const float qs = (t == 0) ? QSCALE : 1.f;
#pragma unroll
      for (int ti = 0; ti < 4; ++ti)
#pragma unroll
        for (int r = 0; r < 4; ++r) {
          const int row = tm + wm + ti * 16 + quad * 4 + r;
          const int b = row >> 11, m = row & 2047;
          u16* drow = dst + ((size_t)(b * 16 + h) * 2048 + m) * 64;
#pragma unroll
          for (int tj = 0; tj < 2; ++tj) {
            const int i = tj * 16 + l15;                 // freq index 0..31
            const float x1 = acc[ti][tj][r] + ea.bias[col0 + i];
            const float x2 = acc[ti][tj + 2][r] + ea.bias[col0 + 32 + i];
            const float cs = ea.ct[m * 32 + i];
            const float sn = ea.st[m * 32 + i];
            drow[i] = f2bf((x1 * cs - x2 * sn) * qs);
            drow[32 + i] = f2bf((x1 * sn + x2 * cs) * qs);
          }
        }
    }
  } else {
#pragma unroll
    for (int ti = 0; ti < 4; ++ti)
#pragma unroll
      for (int r = 0; r < 4; ++r) {
        const int row = tm + wm + ti * 16 + quad * 4 + r;
#pragma unroll
        for (int u = 0; u < 2; ++u) {
          const float hin = acc[ti][2 * u][r];
          const float hg = acc[ti][2 * u + 1][r];
          const int a = (((tn + wn) >> 5) + u) * 16 + l15;
          // gelu(h) ~= h * sigmoid(2t), t = 0.7978845608(h + 0.044715 h^3)
          const float t2 = hin + 0.044715f * hin * hin * hin;
          const float e = __builtin_amdgcn_exp2f(t2 * -2.302114768f);  // -2*0.79788*log2e
          const float gl = hin * __builtin_amdgcn_rcpf(1.f + e);
          ea.outbf[(size_t)row * 2624 + a] = f2bf(gl * hg);
        }
      }
  }
}

// ---------------- split-K GEMM: 128x128 tile, bf16 partials ----------------
// z < zsw: kofs=z*kps1, kps=kps1; else kofs=zsw*kps1+(z-zsw)*kps2, kps=kps2
__global__ __launch_bounds__(256, 3)
void gemm_sk4(const u16* __restrict__ A, const u16* __restrict__ B, int K, int NT,
              int kps1, int zsw, int kps2,
              u16* __restrict__ p0, u16* __restrict__ p1,
              u16* __restrict__ p2, u16* __restrict__ p3) {
  __shared__ __align__(16) u16 sA[128 * 32];
  __shared__ __align__(16) u16 sB[128 * 32];
  int tn, tm;
  swizzle_tile(NT, tn, tm);
  const int z = blockIdx.y;
  int kofs, kps;
  if (z < zsw) { kofs = z * kps1; kps = kps1; }
  else { kofs = zsw * kps1 + (z - zsw) * kps2; kps = kps2; }
  const int tid = threadIdx.x;
  const int wave = tid >> 6, lane = tid & 63;
  const int quad = lane >> 4, l15 = lane & 15;
  const int wm = (wave >> 1) * 64, wn = (wave & 1) * 64;

  floatx4 acc[4][4];
#pragma unroll
  for (int i = 0; i < 4; ++i)
#pragma unroll
    for (int j = 0; j < 4; ++j) acc[i][j] = (floatx4){0.f, 0.f, 0.f, 0.f};

  const int srow = lane >> 2;
  const int skc = (lane & 3) * 8;
  const u16* sAr = sA + (wm + l15) * 32 + quad * 8;
  const u16* sBr = sB + (wn + l15) * 32 + quad * 8;

  for (int k0 = 0; k0 < kps; k0 += 32) {
    const int kk = kofs + k0;
#pragma unroll
    for (int j = 0; j < 2; ++j) {
      const int q = wave * 2 + j;
      const int row = q * 16 + srow;
      async_load16(A + (size_t)(tm + row) * K + (kk + skc), (const char*)sA + q * 1024);
      async_load16(B + (size_t)(tn + row) * K + (kk + skc), (const char*)sB + q * 1024);
    }
    __syncthreads();
    short8 af[4], bfr[4];
#pragma unroll
    for (int t = 0; t < 4; ++t) af[t] = *(const short8*)(sAr + t * 512);
#pragma unroll
    for (int t = 0; t < 4; ++t) bfr[t] = *(const short8*)(sBr + t * 512);
#pragma unroll
    for (int ti = 0; ti < 4; ++ti)
#pragma unroll
      for (int tj = 0; tj < 4; ++tj)
        acc[ti][tj] = __builtin_amdgcn_mfma_f32_16x16x32_bf16(af[ti], bfr[tj], acc[ti][tj], 0, 0, 0);
    __syncthreads();
  }

  u16* part = (z == 0) ? p0 : (z == 1) ? p1 : (z == 2) ? p2 : p3;
#pragma unroll
  for (int ti = 0; ti < 4; ++ti)
#pragma unroll
    for (int r = 0; r < 4; ++r) {
      const int row = tm + wm + ti * 16 + quad * 4 + r;
#pragma unroll
      for (int tj = 0; tj < 4; ++tj)
        part[(size_t)row * 1024 + tn + wn + tj * 16 + l15] = f2bf(acc[ti][tj][r]);
    }
}

// ---------------- flash attention, split-K=2, swapped QK^T ----------------
// r6 post-mortem: kb-hoist regressed (dependency wall + VGPR 64->80 cut
// intra-SIMD slack). The LDS-traffic theory stands (r5: 528 cyc/tile/wave
// ~= 56us ~= dur). This round removes the single largest LDS cost -- the
// P-pack LDS round trip (16 ds_write + 4 ds_read + 4 SERIAL lgkmcnt waits
// per tile/wave) -- by computing QK^T SWAPPED: sacc = mfma(K_frag, Q_frag)
// gives S^T, so each lane holds 16 scores for ONE q-row (l15) at keys
// {tj*16+quad*4+r}. The PV A-fragment (lane=row l15, k=quad*8+j) is then
// built with 8 in-lane register perms; the key-index mapping j=(t&1)*4+r,
// c=t>>1 is absorbed into the vt store permutation (bits m4m3m2m1m0 ->
// m3m2m4m1m0 within 32-key blocks). Both g-halves' P fragments fit in 16
// regs (pa[2][2] short8) so PV reads each V fragment ONCE for both g:
// per-tile LDS drops 528 -> 288 cyc/wave (16 K + 8 V b128 reads, zero
// wave-local round trips). sP deleted: LDS 37,888 -> 32,768. li is one
// scalar/lane (q=l15); final reduce = shfl_xor 16,32.
DEVFN void attn_stage64(const u16* __restrict__ kg, const u16* __restrict__ vtg,
                        size_t bhk, size_t bhv, int key0, int wave, int lane,
                        const u16* sK, const u16* sV) {
#pragma unroll
  for (int j = 0; j < 4; ++j) {
    const int qi = wave * 4 + j;
    if (qi < 8) {
      // K chunk qi: key row = lane, dh range [qi*8, qi*8+8)
      async_load16(kg + bhk + (size_t)(key0 + lane) * 64 + qi * 8,
                   (const char*)sK + qi * 1024);
    } else {
      // V slot vi: dh row = lane, keys (permuted) c*32+kc*8..+8
      const int vi = qi - 8;
      const int c = vi >> 2, kc = vi & 3;
      async_load16(vtg + bhv + (size_t)lane * 2048 + key0 + c * 32 + kc * 8,
                   (const char*)sV + vi * 1024);
    }
  }
}

__global__ __launch_bounds__(256, 3)
void attn_k(const u16* __restrict__ qg, const u16* __restrict__ kg,
            const u16* __restrict__ vtg, const int* __restrict__ mask,
            u16* __restrict__ p0g, u16* __restrict__ p1g,
            float* __restrict__ li0, float* __restrict__ li1) {
  __shared__ __align__(16) u16 sKV[2][8192];     // [buf][ K 4096 u16 | V 4096 u16 ]
  // block remap: 4 consecutive heads per XCD (round-robin dispatch heuristic)
  const int L = blockIdx.x;                      // 1024
  const int xcd = L & 7, idx = L >> 3;           // idx 0..127
  const int bh = (xcd << 2) | (idx >> 5);
  const int local = idx & 31;                    // 16 q-tiles x 2 ksplit
  const int q0 = (local >> 1) * 128;
  const int z = local & 1;
  const int keyBase = z << 10;                   // 0 or 1024
  const int b = bh >> 4, h = bh & 15;
  const int tid = threadIdx.x;
  const int wave = tid >> 6, lane = tid & 63;
  const int quad = lane >> 4, l15 = lane & 15;
  const size_t bhk = (size_t)bh * 2048 * 64;     // kg base for this head
  const size_t bhv = (size_t)bh * 64 * 2048;     // vtg base

  short8 aq[2][2];
#pragma unroll
  for (int g = 0; g < 2; ++g) {
    const u16* qptr = qg + ((size_t)bh * 2048 + q0 + wave * 32 + g * 16 + l15) * 64 + quad * 8;
    aq[g][0] = *(const short8*)qptr;
    aq[g][1] = *(const short8*)(qptr + 32);
  }

  floatx4 o[2][4];
#pragma unroll
  for (int g = 0; g < 2; ++g)
#pragma unroll
    for (int t = 0; t < 4; ++t) o[g][t] = (floatx4){0.f, 0.f, 0.f, 0.f};
  float li[2] = {0.f, 0.f};
  const floatx4 z4 = {0.f, 0.f, 0.f, 0.f};

  attn_stage64(kg, vtg, bhk, bhv, keyBase, wave, lane, sKV[0], sKV[0] + 4096);
  __syncthreads();

  int buf = 0;
  for (int kt = 0; kt < 16; ++kt) {
    const u16* sK = sKV[buf];
    const u16* sV = sKV[buf] + 4096;
    const int key0 = keyBase + kt * 64;
    if (kt < 15) {
      // prefetch next K/V tile into the other buffer
      attn_stage64(kg, vtg, bhk, bhv, key0 + 64, wave, lane,
                   sKV[buf ^ 1], sKV[buf ^ 1] + 4096);
    }
    // all-valid check: one key per lane (consumed after QK^T g=0)
    const bool allv = __all(mask[b * 2048 + key0 + lane] > 0);

    short8 pa[2][2];                             // [g][c] P A-fragments
#pragma unroll
    for (int g = 0; g < 2; ++g) {
      // swapped QK^T: sacc = S^T -> lane holds q=l15, keys tj*16+quad*4+r
      floatx4 sacc[4];
      __builtin_amdgcn_s_setprio(1);
#pragma unroll
      for (int tj = 0; tj < 4; ++tj) {
        const short8 b0 = *(const short8*)(sK + quad * 512 + (tj * 16 + l15) * 8);
        const short8 b1 = *(const short8*)(sK + (4 + quad) * 512 + (tj * 16 + l15) * 8);
        sacc[tj] = __builtin_amdgcn_mfma_f32_16x16x32_bf16(b0, aq[g][0], z4, 0, 0, 0);
        sacc[tj] = __builtin_amdgcn_mfma_f32_16x16x32_bf16(b1, aq[g][1], sacc[tj], 0, 0, 0);
      }
      __builtin_amdgcn_s_setprio(0);

      // exp + per-lane denominator; add-free fast path for all-valid tiles
      if (allv) {
        float sum = li[g];
#pragma unroll
        for (int tj = 0; tj < 4; ++tj)
#pragma unroll
          for (int r = 0; r < 4; ++r) {
            const float p = __builtin_amdgcn_exp2f(sacc[tj][r]);
            sacc[tj][r] = p;
            sum += p;
          }
        li[g] = sum;
      } else {
        float sum = li[g];
#pragma unroll
        for (int tj = 0; tj < 4; ++tj)
#pragma unroll
          for (int r = 0; r < 4; ++r) {
            const int key = key0 + tj * 16 + quad * 4 + r;
            const float mb = (mask[b * 2048 + key] > 0) ? 0.f : -1e30f;
            const float p = __builtin_amdgcn_exp2f(sacc[tj][r] + mb);
            sacc[tj][r] = p;
            sum += p;
          }
        li[g] = sum;
      }

      // in-register P pack: chunk c uses sacc[2c], sacc[2c+1]
#pragma unroll
      for (int c = 0; c < 2; ++c) {
        uintx4 w;
        w.x = pkbf(sacc[2 * c][0], sacc[2 * c][1]);
        w.y = pkbf(sacc[2 * c][2], sacc[2 * c][3]);
        w.z = pkbf(sacc[2 * c + 1][0], sacc[2 * c + 1][1]);
        w.w = pkbf(sacc[2 * c + 1][2], sacc[2 * c + 1][3]);
        pa[g][c] = __builtin_bit_cast(short8, w);
      }
    }

    // PV: each V fragment read once, used by both g halves
#pragma unroll
    for (int c = 0; c < 2; ++c) {
      __builtin_amdgcn_s_setprio(1);
#pragma unroll
      for (int tj2 = 0; tj2 < 4; ++tj2) {
        const short8 bv = *(const short8*)(sV + (c * 4 + quad) * 512 + (tj2 * 16 + l15) * 8);
        o[0][tj2] = __builtin_amdgcn_mfma_f32_16x16x32_bf16(pa[0][c], bv, o[0][tj2], 0, 0, 0);
        o[1][tj2] = __builtin_amdgcn_mfma_f32_16x16x32_bf16(pa[1][c], bv, o[1][tj2], 0, 0, 0);
      }
      __builtin_amdgcn_s_setprio(0);
    }
    __syncthreads();
    buf ^= 1;
  }

  // li: sum the 4 quad partials for each q=l15; all lanes end with the total
#pragma unroll
  for (int g = 0; g < 2; ++g) {
    float s = li[g];
    s += __shfl_xor(s, 16);
    s += __shfl_xor(s, 32);
    li[g] = s;
  }

  u16* pz = z ? p1g : p0g;
  float* lz = z ? li1 : li0;
  if (lane < 16) {
#pragma unroll
    for (int g = 0; g < 2; ++g)
      lz[(size_t)bh * 2048 + q0 + wave * 32 + g * 16 + l15] = li[g];
  }

#pragma unroll
  for (int g = 0; g < 2; ++g)
#pragma unroll
    for (int tj = 0; tj < 4; ++tj)
#pragma unroll
      for (int r = 0; r < 4; ++r) {
        const int m = q0 + wave * 32 + g * 16 + quad * 4 + r;
        pz[((size_t)b * 2048 + m) * 1024 + h * 64 + tj * 16 + l15] = f2bf(o[g][tj][r]);
      }
}

// ---------------- host ----------------
// ws layout (bytes)
static const size_t OFF_WQKV = 0;                       // 3072*1024 bf16; attn li / mlp partial3
static const size_t OFF_WO   = 6291456;                 // 1024*1024 bf16
static const size_t OFF_WI   = 8388608;                 // 5248*1024 bf16; -> mlp partial2
static const size_t OFF_WMLP = 19136512;                // 1024*2624 bf16
static const size_t OFF_XN   = 24510464;                // xn / attn p0 / xn2 / mlp partial0
static const size_t OFF_Q    = 32899072;                // q -> Wo partial0 -> act[0:]
static const size_t OFF_K    = 41287680;                // k -> Wo partial1 -> act cont.
static const size_t OFF_VT   = 49676288;                // vt -> Wo partial2 -> act tail
static const size_t OFF_ATT  = 58064896;                // rope -> attn p1 -> att -> mlp partial1
static const size_t OFF_ROPE = OFF_ATT;
static const size_t WS_NEED  = 66453504;

extern "C" void kernel_launch(void* const* d_in, const int* in_sizes, int n_in,
                              void* d_out, int out_size, void* d_ws, size_t ws_size,
                              hipStream_t stream) {
  (void)in_sizes; (void)n_in; (void)out_size;
  if (ws_size < WS_NEED) return;

  const float* hidden = (const float*)d_in[0];
  const int*   mask   = (const int*)d_in[1];
  const float* ln1g   = (const float*)d_in[2];
  const float* ln1b   = (const float*)d_in[3];
  const float* Wqkv   = (const float*)d_in[4];
  const float* Wqkvb  = (const float*)d_in[5];
  const float* Wo     = (const float*)d_in[6];
  const float* ln2g   = (const float*)d_in[7];
  const float* ln2b   = (const float*)d_in[8];
  const float* Wi     = (const float*)d_in[9];
  const float* Wmlp   = (const float*)d_in[10];
  float* out = (float*)d_out;
  char* ws = (char*)d_ws;

  u16* wqkv_bf = (u16*)(ws + OFF_WQKV);
  u16* wo_bf   = (u16*)(ws + OFF_WO);
  u16* wi_bf   = (u16*)(ws + OFF_WI);
  u16* wmlp_bf = (u16*)(ws + OFF_WMLP);
  u16* xn      = (u16*)(ws + OFF_XN);
  u16* qb      = (u16*)(ws + OFF_Q);
  u16* kb      = (u16*)(ws + OFF_K);
  u16* vtb     = (u16*)(ws + OFF_VT);
  u16* att     = (u16*)(ws + OFF_ATT);
  u16* act     = (u16*)(ws + OFF_Q);                    // 21.5MB spans q/k/vt regions
  float* ct    = (float*)(ws + OFF_ROPE);
  float* st    = (float*)(ws + OFF_ROPE + 262144);
  u16* ap0     = (u16*)(ws + OFF_XN);                   // attn partial z=0 (xn dead)
  u16* ap1     = (u16*)(ws + OFF_ATT);                  // attn partial z=1 (= att, in-place)
  float* li0   = (float*)(ws + OFF_WQKV);               // wqkv_bf dead post-QKV gemm
  float* li1   = (float*)(ws + OFF_WQKV + 262144);
  u16* wp0     = (u16*)(ws + OFF_Q);                    // Wo partials (q/k/vt dead post-attn)
  u16* wp1     = (u16*)(ws + OFF_K);
  u16* wp2     = (u16*)(ws + OFF_VT);
  u16* mp0     = (u16*)(ws + OFF_XN);                   // xn dead after Wi gemm
  u16* mp1     = (u16*)(ws + OFF_ATT);                  // att dead after Wo gemm
  u16* mp2     = (u16*)(ws + OFF_WI);                   // wi_bf dead after Wi gemm
  u16* mp3     = (u16*)(ws + OFF_WQKV);                 // wqkv+li dead by mlp time

  prep_k<<<16320, 256, 0, stream>>>(Wqkv, Wo, Wi, Wmlp, hidden, ln1g, ln1b,
                                    wqkv_bf, wo_bf, wi_bf, wmlp_bf, ct, st, xn);

  EpiArgs e1 = {Wqkvb, qb, kb, vtb, nullptr, ct, st};
  gemm_k<0><<<768, 256, 0, stream>>>(xn, wqkv_bf, 1024, 24, e1);

  attn_k<<<dim3(1024), 256, 0, stream>>>(qb, kb, vtb, mask, ap0, ap1, li0, li1);
  red_att_k<<<4096, 256, 0, stream>>>(att, ap0, li0, li1);

  gemm_sk4<<<dim3(256, 3), 256, 0, stream>>>(att, wo_bf, 1024, 8, 352, 2, 320,
                                             wp0, wp1, wp2, wp2);
  red_ln_k<<<4096, 256, 0, stream>>>(hidden, wp0, wp1, wp2, ln2g, ln2b, out, xn);

  EpiArgs e3 = {nullptr, nullptr, nullptr, nullptr, act, nullptr, nullptr};
  gemm_k<2><<<1312, 256, 0, stream>>>(xn, wi_bf, 1024, 41, e3);

  gemm_sk4<<<dim3(256, 4), 256, 0, stream>>>(act, wmlp_bf, 2624, 8, 672, 2, 640,
                                             mp0, mp1, mp2, mp3);
  red_add_k<<<4096, 256, 0, stream>>>(out, mp0, mp1, mp2, mp3);
}

// Round 8
// 331.746 us; speedup vs baseline: 1.1090x; 1.0412x over previous
//
#include <hip/hip_runtime.h>
#include <cstdint>
#include <cstddef>

using u16 = unsigned short;
using u32 = uint32_t;

typedef __attribute__((ext_vector_type(8))) short short8;
typedef __attribute__((ext_vector_type(4))) float floatx4;
typedef __attribute__((ext_vector_type(4))) unsigned int uintx4;

#define DEVFN static __device__ __forceinline__

// 0.125 * log2(e): fold attention scale into q, softmax runs in log2 domain
#define QSCALE 0.18033688011112042f

DEVFN u16 f2bf(float f) {
  u32 u = __float_as_uint(f);
  return (u16)((u + 0x7fffu + ((u >> 16) & 1u)) >> 16);
}

DEVFN float b2f(u16 u) { return __uint_as_float(((u32)u) << 16); }

// pack two f32 -> u32 of 2 bf16 (lo in low half); round-add as elsewhere
DEVFN u32 pkbf(float lo, float hi) {
  return __builtin_amdgcn_perm(__float_as_uint(hi) + 0x8000u,
                               __float_as_uint(lo) + 0x8000u, 0x07060302u);
}

DEVFN void async_load16(const void* g, const void* lds) {
  __builtin_amdgcn_global_load_lds(
      (const __attribute__((address_space(1))) u32*)(uintptr_t)g,
      (__attribute__((address_space(3))) u32*)(u32)(uintptr_t)lds,
      16, 0, 0);
}

DEVFN void cvt4(const float* __restrict__ src, u16* __restrict__ dst, int i) {
  const float4 v = ((const float4*)src)[i];
  ushort4 o;
  o.x = f2bf(v.x); o.y = f2bf(v.y); o.z = f2bf(v.z); o.w = f2bf(v.w);
  ((ushort4*)dst)[i] = o;
}

// ---------------- fused prep: rope tables + all weight cvts + LN1 ----------------
// grid ranges: [0,256) rope | [256,3328) Wqkv | [3328,4352) Wo |
//              [4352,9600) Wi-permute | [9600,12224) Wmlp | [12224,16320) LN1
__global__ __launch_bounds__(256)
void prep_k(const float* __restrict__ Wqkv, const float* __restrict__ Wo,
            const float* __restrict__ Wi, const float* __restrict__ Wmlp,
            const float* __restrict__ hidden, const float* __restrict__ ln1g,
            const float* __restrict__ ln1b,
            u16* __restrict__ wqkv_bf, u16* __restrict__ wo_bf,
            u16* __restrict__ wi_bf, u16* __restrict__ wmlp_bf,
            float* __restrict__ ct, float* __restrict__ st, u16* __restrict__ xn) {
  const int bid = blockIdx.x;
  const int tid = threadIdx.x;
  __shared__ float red[8];
  if (bid < 256) {
    const int i = bid * 256 + tid;
    const int m = i >> 5, f = i & 31;
    const float inv = exp2f((float)f * -0.41524101186092025f);  // 10000^(-f/32)
    const float ang = (float)m * inv;
    ct[i] = cosf(ang);
    st[i] = sinf(ang);
  } else if (bid < 3328) {
    cvt4(Wqkv, wqkv_bf, (bid - 256) * 256 + tid);
  } else if (bid < 4352) {
    cvt4(Wo, wo_bf, (bid - 3328) * 256 + tid);
  } else if (bid < 9600) {
    // Wi permute: dst row p=g*32+c: c<16 -> Wi row g*16+c, else 2624+g*16+(c-16)
    const int i = (bid - 4352) * 256 + tid;
    const int i4 = i * 4;
    const int p = i4 >> 10, kc = i4 & 1023;
    const int g = p >> 5, c = p & 31;
    const int srow = (c < 16) ? (g * 16 + c) : (2624 + g * 16 + (c - 16));
    const float4 v = *(const float4*)(Wi + (size_t)srow * 1024 + kc);
    ushort4 o;
    o.x = f2bf(v.x); o.y = f2bf(v.y); o.z = f2bf(v.z); o.w = f2bf(v.w);
    ((ushort4*)wi_bf)[i] = o;
  } else if (bid < 12224) {
    cvt4(Wmlp, wmlp_bf, (bid - 9600) * 256 + tid);
  } else {
    const int row = bid - 12224;
    const float4 v = ((const float4*)(hidden + (size_t)row * 1024))[tid];
    float s = v.x + v.y + v.z + v.w;
    float ss = v.x * v.x + v.y * v.y + v.z * v.z + v.w * v.w;
#pragma unroll
    for (int d = 32; d > 0; d >>= 1) {
      s += __shfl_xor(s, d);
      ss += __shfl_xor(ss, d);
    }
    const int wave = tid >> 6;
    if ((tid & 63) == 0) { red[wave] = s; red[4 + wave] = ss; }
    __syncthreads();
    s = red[0] + red[1] + red[2] + red[3];
    ss = red[4] + red[5] + red[6] + red[7];
    const float mu = s * (1.f / 1024.f);
    const float var = ss * (1.f / 1024.f) - mu * mu;
    const float rr = rsqrtf(var + 1e-5f);
    const float4 gv = ((const float4*)ln1g)[tid];
    const float4 bv = ((const float4*)ln1b)[tid];
    u16* orow = xn + (size_t)row * 1024 + tid * 4;
    orow[0] = f2bf((v.x - mu) * rr * gv.x + bv.x);
    orow[1] = f2bf((v.y - mu) * rr * gv.y + bv.y);
    orow[2] = f2bf((v.z - mu) * rr * gv.z + bv.z);
    orow[3] = f2bf((v.w - mu) * rr * gv.w + bv.w);
  }
}

// ---------------- reduce 3 partials + residual + layernorm ----------------
__global__ __launch_bounds__(256)
void red_ln_k(const float* __restrict__ resid, const u16* __restrict__ p0,
              const u16* __restrict__ p1, const u16* __restrict__ p2,
              const float* __restrict__ g, const float* __restrict__ bb,
              float* __restrict__ outx, u16* __restrict__ outn) {
  const int row = blockIdx.x;
  const int tid = threadIdx.x;
  const size_t base = (size_t)row * 1024;
  const float4 h = ((const float4*)(resid + base))[tid];
  const ushort4 a = ((const ushort4*)(p0 + base))[tid];
  const ushort4 c = ((const ushort4*)(p1 + base))[tid];
  const ushort4 d = ((const ushort4*)(p2 + base))[tid];
  float4 v;
  v.x = h.x + b2f(a.x) + b2f(c.x) + b2f(d.x);
  v.y = h.y + b2f(a.y) + b2f(c.y) + b2f(d.y);
  v.z = h.z + b2f(a.z) + b2f(c.z) + b2f(d.z);
  v.w = h.w + b2f(a.w) + b2f(c.w) + b2f(d.w);
  float s = v.x + v.y + v.z + v.w;
  float ss = v.x * v.x + v.y * v.y + v.z * v.z + v.w * v.w;
#pragma unroll
  for (int dd = 32; dd > 0; dd >>= 1) {
    s += __shfl_xor(s, dd);
    ss += __shfl_xor(ss, dd);
  }
  __shared__ float red[8];
  const int wave = tid >> 6;
  if ((tid & 63) == 0) { red[wave] = s; red[4 + wave] = ss; }
  __syncthreads();
  s = red[0] + red[1] + red[2] + red[3];
  ss = red[4] + red[5] + red[6] + red[7];
  const float mu = s * (1.f / 1024.f);
  const float var = ss * (1.f / 1024.f) - mu * mu;
  const float rr = rsqrtf(var + 1e-5f);
  ((float4*)(outx + base))[tid] = v;
  const float4 gv = ((const float4*)g)[tid];
  const float4 bv = ((const float4*)bb)[tid];
  u16* orow = outn + base + tid * 4;
  orow[0] = f2bf((v.x - mu) * rr * gv.x + bv.x);
  orow[1] = f2bf((v.y - mu) * rr * gv.y + bv.y);
  orow[2] = f2bf((v.z - mu) * rr * gv.z + bv.z);
  orow[3] = f2bf((v.w - mu) * rr * gv.w + bv.w);
}

// ---------------- final: out += p0+p1+p2+p3 ----------------
__global__ void red_add_k(float* __restrict__ out, const u16* __restrict__ p0,
                          const u16* __restrict__ p1, const u16* __restrict__ p2,
                          const u16* __restrict__ p3) {
  const int i = blockIdx.x * 256 + threadIdx.x;  // 1048576
  float4 v = ((const float4*)out)[i];
  const ushort4 a = ((const ushort4*)p0)[i];
  const ushort4 c = ((const ushort4*)p1)[i];
  const ushort4 d = ((const ushort4*)p2)[i];
  const ushort4 e = ((const ushort4*)p3)[i];
  v.x += b2f(a.x) + b2f(c.x) + b2f(d.x) + b2f(e.x);
  v.y += b2f(a.y) + b2f(c.y) + b2f(d.y) + b2f(e.y);
  v.z += b2f(a.z) + b2f(c.z) + b2f(d.z) + b2f(e.z);
  v.w += b2f(a.w) + b2f(c.w) + b2f(d.w) + b2f(e.w);
  ((float4*)out)[i] = v;
}

// ---------------- attn split-K combine: att = (p0+p1) / (li0+li1) ----------
// In-place over p1 (att aliases p1): elementwise, each thread owns its 4 elems.
__global__ __launch_bounds__(256)
void red_att_k(u16* __restrict__ att, const u16* __restrict__ p0,
               const float* __restrict__ li0, const float* __restrict__ li1) {
  const int i = blockIdx.x * 256 + threadIdx.x;  // 1048576
  const int i4 = i * 4;
  const int row = i4 >> 10;          // b*2048 + m
  const int col = i4 & 1023;
  const int b = row >> 11, m = row & 2047;
  const int h = col >> 6;
  const int bhm = (b * 16 + h) * 2048 + m;
  const float rl = 1.f / (li0[bhm] + li1[bhm]);
  const ushort4 a = ((const ushort4*)p0)[i];
  const ushort4 c = ((const ushort4*)att)[i];
  ushort4 o;
  o.x = f2bf((b2f(a.x) + b2f(c.x)) * rl);
  o.y = f2bf((b2f(a.y) + b2f(c.y)) * rl);
  o.z = f2bf((b2f(a.z) + b2f(c.z)) * rl);
  o.w = f2bf((b2f(a.w) + b2f(c.w)) * rl);
  ((ushort4*)att)[i] = o;
}

// XCD-rectangle swizzle: linear dispatch p -> (tn, tm). Round-robin XCD
// assignment (p%8) gets a contiguous logical range; GROUP_M=8 banding makes
// the ~32 concurrent blocks per XCD an 8m x 4n rectangle (~3MB, fits 4MB L2).
DEVFN void swizzle_tile(int NT, int& tn, int& tm) {
  const int tpx = gridDim.x >> 3;
  const int p = blockIdx.x;
  const int lid = (p & 7) * tpx + (p >> 3);
  const int band = lid / (8 * NT);
  const int rem = lid - band * 8 * NT;
  tn = (rem >> 3) * 128;
  tm = (band * 8 + (rem & 7)) * 128;
}

// ---------------- GEMM: C = A @ B^T, 128x128 tile, BK=32 ----------------
struct EpiArgs {
  const float* bias;
  u16* q; u16* kk; u16* vt;
  u16* outbf;
  const float* ct; const float* st;
};

// EPI 0: QKV (bias + rope + scatter to q/k/vt; q pre-scaled; vt key-permuted)
// EPI 2: gelu-gate -> outbf (act, width 2624)
template <int EPI>
__global__ __launch_bounds__(256, 3)
void gemm_k(const u16* __restrict__ A, const u16* __restrict__ B, int K, int NT,
            EpiArgs ea) {
  __shared__ __align__(16) u16 sA[128 * 32];
  __shared__ __align__(16) u16 sB[128 * 32];
  int tn, tm;
  swizzle_tile(NT, tn, tm);
  const int tid = threadIdx.x;
  const int wave = tid >> 6, lane = tid & 63;
  const int quad = lane >> 4, l15 = lane & 15;
  const int wm = (wave >> 1) * 64, wn = (wave & 1) * 64;

  floatx4 acc[4][4];
#pragma unroll
  for (int i = 0; i < 4; ++i)
#pragma unroll
    for (int j = 0; j < 4; ++j) acc[i][j] = (floatx4){0.f, 0.f, 0.f, 0.f};

  const int srow = lane >> 2;
  const int skc = (lane & 3) * 8;
  const u16* sAr = sA + (wm + l15) * 32 + quad * 8;
  const u16* sBr = sB + (wn + l15) * 32 + quad * 8;

  for (int k0 = 0; k0 < K; k0 += 32) {
#pragma unroll
    for (int j = 0; j < 2; ++j) {
      const int q = wave * 2 + j;
      const int row = q * 16 + srow;
      async_load16(A + (size_t)(tm + row) * K + (k0 + skc), (const char*)sA + q * 1024);
      async_load16(B + (size_t)(tn + row) * K + (k0 + skc), (const char*)sB + q * 1024);
    }
    __syncthreads();
    short8 af[4], bfr[4];
#pragma unroll
    for (int t = 0; t < 4; ++t) af[t] = *(const short8*)(sAr + t * 512);
#pragma unroll
    for (int t = 0; t < 4; ++t) bfr[t] = *(const short8*)(sBr + t * 512);
#pragma unroll
    for (int ti = 0; ti < 4; ++ti)
#pragma unroll
      for (int tj = 0; tj < 4; ++tj)
        acc[ti][tj] = __builtin_amdgcn_mfma_f32_16x16x32_bf16(af[ti], bfr[tj], acc[ti][tj], 0, 0, 0);
    __syncthreads();
  }

  if constexpr (EPI == 0) {
    const int col0 = tn + wn;            // multiple of 64 -> one head per wave
    const int t = col0 >> 10;            // 0=q 1=k 2=v
    const int h = (col0 & 1023) >> 6;
    if (t == 2) {
      // vt with key-permuted token positions matching the swapped-QKT P-pack:
      // within each 32-key block, key bits m4 m3 m2 m1 m0 -> m3 m2 m4 m1 m0
#pragma unroll
      for (int ti = 0; ti < 4; ++ti)
#pragma unroll
        for (int r = 0; r < 4; ++r) {
          const int row = tm + wm + ti * 16 + quad * 4 + r;
          const int b = row >> 11, m = row & 2047;
          const int mp = (m & ~31) | ((m & 12) << 1) | ((m & 16) >> 2) | (m & 3);
#pragma unroll
          for (int tj = 0; tj < 4; ++tj) {
            const int dh = tj * 16 + l15;
            const float v = acc[ti][tj][r] + ea.bias[col0 + dh];
            ea.vt[((size_t)((b * 16 + h) * 64 + dh)) * 2048 + mp] = f2bf(v);
          }
        }
    } else {
      u16* dst = (t == 0) ? ea.q : ea.kk;
      const float qs = (t == 0) ? QSCALE : 1.f;
#pragma unroll
      for (int ti = 0; ti < 4; ++ti)
#pragma unroll
        for (int r = 0; r < 4; ++r) {
          const int row = tm + wm + ti * 16 + quad * 4 + r;
          const int b = row >> 11, m = row & 2047;
          u16* drow = dst + ((size_t)(b * 16 + h) * 2048 + m) * 64;
#pragma unroll
          for (int tj = 0; tj < 2; ++tj) {
            const int i = tj * 16 + l15;                 // freq index 0..31
            const float x1 = acc[ti][tj][r] + ea.bias[col0 + i];
            const float x2 = acc[ti][tj + 2][r] + ea.bias[col0 + 32 + i];
            const float cs = ea.ct[m * 32 + i];
            const float sn = ea.st[m * 32 + i];
            drow[i] = f2bf((x1 * cs - x2 * sn) * qs);
            drow[32 + i] = f2bf((x1 * sn + x2 * cs) * qs);
          }
        }
    }
  } else {
#pragma unroll
    for (int ti = 0; ti < 4; ++ti)
#pragma unroll
      for (int r = 0; r < 4; ++r) {
        const int row = tm + wm + ti * 16 + quad * 4 + r;
#pragma unroll
        for (int u = 0; u < 2; ++u) {
          const float hin = acc[ti][2 * u][r];
          const float hg = acc[ti][2 * u + 1][r];
          const int a = (((tn + wn) >> 5) + u) * 16 + l15;
          // gelu(h) ~= h * sigmoid(2t), t = 0.7978845608(h + 0.044715 h^3)
          const float t2 = hin + 0.044715f * hin * hin * hin;
          const float e = __builtin_amdgcn_exp2f(t2 * -2.302114768f);  // -2*0.79788*log2e
          const float gl = hin * __builtin_amdgcn_rcpf(1.f + e);
          ea.outbf[(size_t)row * 2624 + a] = f2bf(gl * hg);
        }
      }
  }
}

// ---------------- split-K GEMM: 128x128 tile, bf16 partials ----------------
// z < zsw: kofs=z*kps1, kps=kps1; else kofs=zsw*kps1+(z-zsw)*kps2, kps=kps2
__global__ __launch_bounds__(256, 3)
void gemm_sk4(const u16* __restrict__ A, const u16* __restrict__ B, int K, int NT,
              int kps1, int zsw, int kps2,
              u16* __restrict__ p0, u16* __restrict__ p1,
              u16* __restrict__ p2, u16* __restrict__ p3) {
  __shared__ __align__(16) u16 sA[128 * 32];
  __shared__ __align__(16) u16 sB[128 * 32];
  int tn, tm;
  swizzle_tile(NT, tn, tm);
  const int z = blockIdx.y;
  int kofs, kps;
  if (z < zsw) { kofs = z * kps1; kps = kps1; }
  else { kofs = zsw * kps1 + (z - zsw) * kps2; kps = kps2; }
  const int tid = threadIdx.x;
  const int wave = tid >> 6, lane = tid & 63;
  const int quad = lane >> 4, l15 = lane & 15;
  const int wm = (wave >> 1) * 64, wn = (wave & 1) * 64;

  floatx4 acc[4][4];
#pragma unroll
  for (int i = 0; i < 4; ++i)
#pragma unroll
    for (int j = 0; j < 4; ++j) acc[i][j] = (floatx4){0.f, 0.f, 0.f, 0.f};

  const int srow = lane >> 2;
  const int skc = (lane & 3) * 8;
  const u16* sAr = sA + (wm + l15) * 32 + quad * 8;
  const u16* sBr = sB + (wn + l15) * 32 + quad * 8;

  for (int k0 = 0; k0 < kps; k0 += 32) {
    const int kk = kofs + k0;
#pragma unroll
    for (int j = 0; j < 2; ++j) {
      const int q = wave * 2 + j;
      const int row = q * 16 + srow;
      async_load16(A + (size_t)(tm + row) * K + (kk + skc), (const char*)sA + q * 1024);
      async_load16(B + (size_t)(tn + row) * K + (kk + skc), (const char*)sB + q * 1024);
    }
    __syncthreads();
    short8 af[4], bfr[4];
#pragma unroll
    for (int t = 0; t < 4; ++t) af[t] = *(const short8*)(sAr + t * 512);
#pragma unroll
    for (int t = 0; t < 4; ++t) bfr[t] = *(const short8*)(sBr + t * 512);
#pragma unroll
    for (int ti = 0; ti < 4; ++ti)
#pragma unroll
      for (int tj = 0; tj < 4; ++tj)
        acc[ti][tj] = __builtin_amdgcn_mfma_f32_16x16x32_bf16(af[ti], bfr[tj], acc[ti][tj], 0, 0, 0);
    __syncthreads();
  }

  u16* part = (z == 0) ? p0 : (z == 1) ? p1 : (z == 2) ? p2 : p3;
#pragma unroll
  for (int ti = 0; ti < 4; ++ti)
#pragma unroll
    for (int r = 0; r < 4; ++r) {
      const int row = tm + wm + ti * 16 + quad * 4 + r;
#pragma unroll
      for (int tj = 0; tj < 4; ++tj)
        part[(size_t)row * 1024 + tn + wn + tj * 16 + l15] = f2bf(acc[ti][tj][r]);
    }
}

// ---------------- flash attention, split-K=2, swapped QK^T ----------------
// r7 post-mortem: swapped-QKT removed the P-pack LDS round trip (bank
// conflicts 1M->0) but dur stalled at 67us with all pipes <=36% -- the
// hidden serial stall is the PER-TILE MASK LOAD. vmcnt is an IN-ORDER
// counter: the mask load is issued after the 4 global_load_lds prefetch
// ops, so waiting for the mask value (consumed in the exp phase, ~16 MFMAs
// of cover) forces vmcnt(0) == all prefetch DMAs complete MID-TILE --
// destroying the double-buffer overlap every tile. Fix: precompute a
// 16-bit all-valid bitmask (avbits) for all 16 kv-tiles BEFORE the loop;
// the loop then has zero VMEM consumers -- the only VMEM ops are the 4
// prefetch DMAs whose single consumer is the end-of-tile barrier (full
// tile of compute cover, as designed). Non-all-valid path (never taken on
// all-ones masks) loads per-key mask inside its wave-uniform branch.
DEVFN void attn_stage64(const u16* __restrict__ kg, const u16* __restrict__ vtg,
                        size_t bhk, size_t bhv, int key0, int wave, int lane,
                        const u16* sK, const u16* sV) {
#pragma unroll
  for (int j = 0; j < 4; ++j) {
    const int qi = wave * 4 + j;
    if (qi < 8) {
      // K chunk qi: key row = lane, dh range [qi*8, qi*8+8)
      async_load16(kg + bhk + (size_t)(key0 + lane) * 64 + qi * 8,
                   (const char*)sK + qi * 1024);
    } else {
      // V slot vi: dh row = lane, keys (permuted) c*32+kc*8..+8
      const int vi = qi - 8;
      const int c = vi >> 2, kc = vi & 3;
      async_load16(vtg + bhv + (size_t)lane * 2048 + key0 + c * 32 + kc * 8,
                   (const char*)sV + vi * 1024);
    }
  }
}

__global__ __launch_bounds__(256, 3)
void attn_k(const u16* __restrict__ qg, const u16* __restrict__ kg,
            const u16* __restrict__ vtg, const int* __restrict__ mask,
            u16* __restrict__ p0g, u16* __restrict__ p1g,
            float* __restrict__ li0, float* __restrict__ li1) {
  __shared__ __align__(16) u16 sKV[2][8192];     // [buf][ K 4096 u16 | V 4096 u16 ]
  // block remap: 4 consecutive heads per XCD (round-robin dispatch heuristic)
  const int L = blockIdx.x;                      // 1024
  const int xcd = L & 7, idx = L >> 3;           // idx 0..127
  const int bh = (xcd << 2) | (idx >> 5);
  const int local = idx & 31;                    // 16 q-tiles x 2 ksplit
  const int q0 = (local >> 1) * 128;
  const int z = local & 1;
  const int keyBase = z << 10;                   // 0 or 1024
  const int b = bh >> 4, h = bh & 15;
  const int tid = threadIdx.x;
  const int wave = tid >> 6, lane = tid & 63;
  const int quad = lane >> 4, l15 = lane & 15;
  const size_t bhk = (size_t)bh * 2048 * 64;     // kg base for this head
  const size_t bhv = (size_t)bh * 64 * 2048;     // vtg base

  // precompute per-tile all-valid bits (zero VMEM inside the K-loop)
  u32 avbits = 0;
#pragma unroll
  for (int kt = 0; kt < 16; ++kt) {
    const bool ok = mask[b * 2048 + keyBase + kt * 64 + lane] > 0;
    if (__all(ok)) avbits |= (1u << kt);
  }

  short8 aq[2][2];
#pragma unroll
  for (int g = 0; g < 2; ++g) {
    const u16* qptr = qg + ((size_t)bh * 2048 + q0 + wave * 32 + g * 16 + l15) * 64 + quad * 8;
    aq[g][0] = *(const short8*)qptr;
    aq[g][1] = *(const short8*)(qptr + 32);
  }

  floatx4 o[2][4];
#pragma unroll
  for (int g = 0; g < 2; ++g)
#pragma unroll
    for (int t = 0; t < 4; ++t) o[g][t] = (floatx4){0.f, 0.f, 0.f, 0.f};
  float li[2] = {0.f, 0.f};
  const floatx4 z4 = {0.f, 0.f, 0.f, 0.f};

  attn_stage64(kg, vtg, bhk, bhv, keyBase, wave, lane, sKV[0], sKV[0] + 4096);
  __syncthreads();

  int buf = 0;
  for (int kt = 0; kt < 16; ++kt) {
    const u16* sK = sKV[buf];
    const u16* sV = sKV[buf] + 4096;
    const int key0 = keyBase + kt * 64;
    if (kt < 15) {
      // prefetch next K/V tile into the other buffer; sole consumer is the
      // end-of-tile barrier -> full tile of compute cover
      attn_stage64(kg, vtg, bhk, bhv, key0 + 64, wave, lane,
                   sKV[buf ^ 1], sKV[buf ^ 1] + 4096);
    }
    const bool allv = (avbits >> kt) & 1u;

    short8 pa[2][2];                             // [g][c] P A-fragments
#pragma unroll
    for (int g = 0; g < 2; ++g) {
      // swapped QK^T: sacc = S^T -> lane holds q=l15, keys tj*16+quad*4+r
      floatx4 sacc[4];
      __builtin_amdgcn_s_setprio(1);
#pragma unroll
      for (int tj = 0; tj < 4; ++tj) {
        const short8 b0 = *(const short8*)(sK + quad * 512 + (tj * 16 + l15) * 8);
        const short8 b1 = *(const short8*)(sK + (4 + quad) * 512 + (tj * 16 + l15) * 8);
        sacc[tj] = __builtin_amdgcn_mfma_f32_16x16x32_bf16(b0, aq[g][0], z4, 0, 0, 0);
        sacc[tj] = __builtin_amdgcn_mfma_f32_16x16x32_bf16(b1, aq[g][1], sacc[tj], 0, 0, 0);
      }
      __builtin_amdgcn_s_setprio(0);

      // exp + per-lane denominator; add-free fast path for all-valid tiles
      if (allv) {
        float sum = li[g];
#pragma unroll
        for (int tj = 0; tj < 4; ++tj)
#pragma unroll
          for (int r = 0; r < 4; ++r) {
            const float p = __builtin_amdgcn_exp2f(sacc[tj][r]);
            sacc[tj][r] = p;
            sum += p;
          }
        li[g] = sum;
      } else {
        float sum = li[g];
#pragma unroll
        for (int tj = 0; tj < 4; ++tj)
#pragma unroll
          for (int r = 0; r < 4; ++r) {
            const int key = key0 + tj * 16 + quad * 4 + r;
            const float mb = (mask[b * 2048 + key] > 0) ? 0.f : -1e30f;
            const float p = __builtin_amdgcn_exp2f(sacc[tj][r] + mb);
            sacc[tj][r] = p;
            sum += p;
          }
        li[g] = sum;
      }

      // in-register P pack: chunk c uses sacc[2c], sacc[2c+1]
#pragma unroll
      for (int c = 0; c < 2; ++c) {
        uintx4 w;
        w.x = pkbf(sacc[2 * c][0], sacc[2 * c][1]);
        w.y = pkbf(sacc[2 * c][2], sacc[2 * c][3]);
        w.z = pkbf(sacc[2 * c + 1][0], sacc[2 * c + 1][1]);
        w.w = pkbf(sacc[2 * c + 1][2], sacc[2 * c + 1][3]);
        pa[g][c] = __builtin_bit_cast(short8, w);
      }
    }

    // PV: each V fragment read once, used by both g halves
#pragma unroll
    for (int c = 0; c < 2; ++c) {
      __builtin_amdgcn_s_setprio(1);
#pragma unroll
      for (int tj2 = 0; tj2 < 4; ++tj2) {
        const short8 bv = *(const short8*)(sV + (c * 4 + quad) * 512 + (tj2 * 16 + l15) * 8);
        o[0][tj2] = __builtin_amdgcn_mfma_f32_16x16x32_bf16(pa[0][c], bv, o[0][tj2], 0, 0, 0);
        o[1][tj2] = __builtin_amdgcn_mfma_f32_16x16x32_bf16(pa[1][c], bv, o[1][tj2], 0, 0, 0);
      }
      __builtin_amdgcn_s_setprio(0);
    }
    __syncthreads();
    buf ^= 1;
  }

  // li: sum the 4 quad partials for each q=l15; all lanes end with the total
#pragma unroll
  for (int g = 0; g < 2; ++g) {
    float s = li[g];
    s += __shfl_xor(s, 16);
    s += __shfl_xor(s, 32);
    li[g] = s;
  }

  u16* pz = z ? p1g : p0g;
  float* lz = z ? li1 : li0;
  if (lane < 16) {
#pragma unroll
    for (int g = 0; g < 2; ++g)
      lz[(size_t)bh * 2048 + q0 + wave * 32 + g * 16 + l15] = li[g];
  }

#pragma unroll
  for (int g = 0; g < 2; ++g)
#pragma unroll
    for (int tj = 0; tj < 4; ++tj)
#pragma unroll
      for (int r = 0; r < 4; ++r) {
        const int m = q0 + wave * 32 + g * 16 + quad * 4 + r;
        pz[((size_t)b * 2048 + m) * 1024 + h * 64 + tj * 16 + l15] = f2bf(o[g][tj][r]);
      }
}

// ---------------- host ----------------
// ws layout (bytes)
static const size_t OFF_WQKV = 0;                       // 3072*1024 bf16; attn li / mlp partial3
static const size_t OFF_WO   = 6291456;                 // 1024*1024 bf16
static const size_t OFF_WI   = 8388608;                 // 5248*1024 bf16; -> mlp partial2
static const size_t OFF_WMLP = 19136512;                // 1024*2624 bf16
static const size_t OFF_XN   = 24510464;                // xn / attn p0 / xn2 / mlp partial0
static const size_t OFF_Q    = 32899072;                // q -> Wo partial0 -> act[0:]
static const size_t OFF_K    = 41287680;                // k -> Wo partial1 -> act cont.
static const size_t OFF_VT   = 49676288;                // vt -> Wo partial2 -> act tail
static const size_t OFF_ATT  = 58064896;                // rope -> attn p1 -> att -> mlp partial1
static const size_t OFF_ROPE = OFF_ATT;
static const size_t WS_NEED  = 66453504;

extern "C" void kernel_launch(void* const* d_in, const int* in_sizes, int n_in,
                              void* d_out, int out_size, void* d_ws, size_t ws_size,
                              hipStream_t stream) {
  (void)in_sizes; (void)n_in; (void)out_size;
  if (ws_size < WS_NEED) return;

  const float* hidden = (const float*)d_in[0];
  const int*   mask   = (const int*)d_in[1];
  const float* ln1g   = (const float*)d_in[2];
  const float* ln1b   = (const float*)d_in[3];
  const float* Wqkv   = (const float*)d_in[4];
  const float* Wqkvb  = (const float*)d_in[5];
  const float* Wo     = (const float*)d_in[6];
  const float* ln2g   = (const float*)d_in[7];
  const float* ln2b   = (const float*)d_in[8];
  const float* Wi     = (const float*)d_in[9];
  const float* Wmlp   = (const float*)d_in[10];
  float* out = (float*)d_out;
  char* ws = (char*)d_ws;

  u16* wqkv_bf = (u16*)(ws + OFF_WQKV);
  u16* wo_bf   = (u16*)(ws + OFF_WO);
  u16* wi_bf   = (u16*)(ws + OFF_WI);
  u16* wmlp_bf = (u16*)(ws + OFF_WMLP);
  u16* xn      = (u16*)(ws + OFF_XN);
  u16* qb      = (u16*)(ws + OFF_Q);
  u16* kb      = (u16*)(ws + OFF_K);
  u16* vtb     = (u16*)(ws + OFF_VT);
  u16* att     = (u16*)(ws + OFF_ATT);
  u16* act     = (u16*)(ws + OFF_Q);                    // 21.5MB spans q/k/vt regions
  float* ct    = (float*)(ws + OFF_ROPE);
  float* st    = (float*)(ws + OFF_ROPE + 262144);
  u16* ap0     = (u16*)(ws + OFF_XN);                   // attn partial z=0 (xn dead)
  u16* ap1     = (u16*)(ws + OFF_ATT);                  // attn partial z=1 (= att, in-place)
  float* li0   = (float*)(ws + OFF_WQKV);               // wqkv_bf dead post-QKV gemm
  float* li1   = (float*)(ws + OFF_WQKV + 262144);
  u16* wp0     = (u16*)(ws + OFF_Q);                    // Wo partials (q/k/vt dead post-attn)
  u16* wp1     = (u16*)(ws + OFF_K);
  u16* wp2     = (u16*)(ws + OFF_VT);
  u16* mp0     = (u16*)(ws + OFF_XN);                   // xn dead after Wi gemm
  u16* mp1     = (u16*)(ws + OFF_ATT);                  // att dead after Wo gemm
  u16* mp2     = (u16*)(ws + OFF_WI);                   // wi_bf dead after Wi gemm
  u16* mp3     = (u16*)(ws + OFF_WQKV);                 // wqkv+li dead by mlp time

  prep_k<<<16320, 256, 0, stream>>>(Wqkv, Wo, Wi, Wmlp, hidden, ln1g, ln1b,
                                    wqkv_bf, wo_bf, wi_bf, wmlp_bf, ct, st, xn);

  EpiArgs e1 = {Wqkvb, qb, kb, vtb, nullptr, ct, st};
  gemm_k<0><<<768, 256, 0, stream>>>(xn, wqkv_bf, 1024, 24, e1);

  attn_k<<<dim3(1024), 256, 0, stream>>>(qb, kb, vtb, mask, ap0, ap1, li0, li1);
  red_att_k<<<4096, 256, 0, stream>>>(att, ap0, li0, li1);

  gemm_sk4<<<dim3(256, 3), 256, 0, stream>>>(att, wo_bf, 1024, 8, 352, 2, 320,
                                             wp0, wp1, wp2, wp2);
  red_ln_k<<<4096, 256, 0, stream>>>(hidden, wp0, wp1, wp2, ln2g, ln2b, out, xn);

  EpiArgs e3 = {nullptr, nullptr, nullptr, nullptr, act, nullptr, nullptr};
  gemm_k<2><<<1312, 256, 0, stream>>>(xn, wi_bf, 1024, 41, e3);

  gemm_sk4<<<dim3(256, 4), 256, 0, stream>>>(act, wmlp_bf, 2624, 8, 672, 2, 640,
                                             mp0, mp1, mp2, mp3);
  red_add_k<<<4096, 256, 0, stream>>>(out, mp0, mp1, mp2, mp3);
}